// Round 1
// baseline (3251.695 us; speedup 1.0000x reference)
//
#include <hip/hip_runtime.h>
#include <hip/hip_bf16.h>
#include <cstddef>
#include <cstdint>

// MultiHeadAttention: B=2, S=4096, D=512, H=8, HD=64
// Round 1: pure-f32 correctness baseline (no MFMA).
//   y = softmax(mask==0 ? -1e9 : (XWq^T+bq)(XWk^T+bk)^T) (XWv^T+bv)  @ Wo^T + bo
// No 1/sqrt(hd) scaling (reference applies none).

#define S_LEN 4096
#define DMODEL 512
#define NHEAD 8
#define HDIM 64

// ---------------------------------------------------------------------------
// GEMM: Y[n][o] = sum_i X[n][i] * W[o][i] + bias[o]
// mode 0: scatter to head-split layout [B,H,S,HD]; mode 1: flat [N,DMODEL]
// grid (N/64, DMODEL/64), 256 threads, 4x4 micro-tile per thread.
// ---------------------------------------------------------------------------
__global__ __launch_bounds__(256) void gemm_xwt(
    const float* __restrict__ X, const float* __restrict__ W,
    const float* __restrict__ bias, float* __restrict__ Y, int mode)
{
  __shared__ float Xs[64][36];   // [row][k], pad 36 (16B-aligned rows, 2-way-free scalar reads)
  __shared__ float Wt[32][68];   // [k][col], pad 68 (float4 reads, uniform dword banks)

  const int t  = threadIdx.x;
  const int tx = t & 15, ty = t >> 4;
  const int row0 = blockIdx.x * 64, col0 = blockIdx.y * 64;

  float acc[4][4] = {{0.f}};

  for (int k0 = 0; k0 < DMODEL; k0 += 32) {
    __syncthreads();
    // stage X tile 64x32 (float4 coalesced)
    #pragma unroll
    for (int i = 0; i < 2; ++i) {
      int id = i * 256 + t;
      int r = id >> 3;
      int c = (id & 7) << 2;
      const float4 v = *(const float4*)(X + (size_t)(row0 + r) * DMODEL + k0 + c);
      *(float4*)(&Xs[r][c]) = v;
    }
    // stage W tile 64(cols)x32(k), transposed into Wt[k][col]
    #pragma unroll
    for (int i = 0; i < 2; ++i) {
      int id = i * 256 + t;
      int o = id >> 3;
      int c = (id & 7) << 2;
      const float4 v = *(const float4*)(W + (size_t)(col0 + o) * DMODEL + k0 + c);
      Wt[c + 0][o] = v.x; Wt[c + 1][o] = v.y; Wt[c + 2][o] = v.z; Wt[c + 3][o] = v.w;
    }
    __syncthreads();

    #pragma unroll
    for (int kk = 0; kk < 32; ++kk) {
      float4 bv = *(const float4*)(&Wt[kk][tx * 4]);
      float b0 = bv.x, b1 = bv.y, b2 = bv.z, b3 = bv.w;
      float a[4];
      #pragma unroll
      for (int i = 0; i < 4; ++i) a[i] = Xs[ty * 4 + i][kk];
      #pragma unroll
      for (int i = 0; i < 4; ++i) {
        acc[i][0] += a[i] * b0;
        acc[i][1] += a[i] * b1;
        acc[i][2] += a[i] * b2;
        acc[i][3] += a[i] * b3;
      }
    }
  }

  #pragma unroll
  for (int i = 0; i < 4; ++i) {
    int n = row0 + ty * 4 + i;
    #pragma unroll
    for (int j = 0; j < 4; ++j) {
      int o = col0 + tx * 4 + j;
      float val = acc[i][j] + bias[o];
      if (mode == 0) {
        // n = b*S + s ; o = h*HD + hd -> Y[((b*H+h)*S+s)*HD+hd]
        int b = n >> 12;
        int s = n & (S_LEN - 1);
        int h = o >> 6;
        int hd = o & (HDIM - 1);
        Y[(((size_t)(b * NHEAD + h)) * S_LEN + s) * HDIM + hd] = val;
      } else {
        Y[(size_t)n * DMODEL + o] = val;
      }
    }
  }
}

// ---------------------------------------------------------------------------
// Flash attention (f32, online softmax). One block = (b,h, 64 q-rows).
// 4 waves x 16 q-rows. Phase A: lane = k-column. Phase B: lane = head dim.
// ---------------------------------------------------------------------------
__global__ __launch_bounds__(256) void flash_attn(
    const float* __restrict__ Q,   // [B,H,S,HD]
    const float* __restrict__ K,
    const float* __restrict__ V,
    const int*   __restrict__ mask, // [B,S,S]
    float* __restrict__ O)          // [B,S,D] (heads interleaved back)
{
  __shared__ float Qs[64][68];
  __shared__ float Ks[64][68];
  __shared__ float Vs[64][68];
  __shared__ float Ps[4][16][64];

  const int t    = threadIdx.x;
  const int lane = t & 63;
  const int w    = t >> 6;       // wave 0..3
  const int bh   = blockIdx.y;   // b*H + h
  const int b    = bh >> 3;
  const int h    = bh & 7;
  const int q0   = blockIdx.x * 64;

  const float* Qbase = Q + ((size_t)bh * S_LEN + q0) * HDIM;
  const float* Kbase = K + (size_t)bh * S_LEN * HDIM;
  const float* Vbase = V + (size_t)bh * S_LEN * HDIM;
  const int*   mbase = mask + ((size_t)b * S_LEN + q0) * S_LEN;

  // load Q tile 64x64
  #pragma unroll
  for (int i = 0; i < 4; ++i) {
    int id = i * 256 + t;
    int r = id >> 4;
    int c = (id & 15) << 2;
    *(float4*)(&Qs[r][c]) = *(const float4*)(Qbase + (size_t)r * HDIM + c);
  }

  float m[16], l[16], acc[16];
  #pragma unroll
  for (int r = 0; r < 16; ++r) { m[r] = -3.0e38f; l[r] = 0.f; acc[r] = 0.f; }

  __syncthreads();

  for (int k0 = 0; k0 < S_LEN; k0 += 64) {
    // stage K,V tiles (64x64 each)
    #pragma unroll
    for (int i = 0; i < 4; ++i) {
      int id = i * 256 + t;
      int r = id >> 4;
      int c = (id & 15) << 2;
      *(float4*)(&Ks[r][c]) = *(const float4*)(Kbase + (size_t)(k0 + r) * HDIM + c);
      *(float4*)(&Vs[r][c]) = *(const float4*)(Vbase + (size_t)(k0 + r) * HDIM + c);
    }
    __syncthreads();

    // ---- Phase A: scores s[r] for k-col = lane ----
    float s[16];
    #pragma unroll
    for (int r = 0; r < 16; ++r) s[r] = 0.f;
    #pragma unroll
    for (int d4 = 0; d4 < HDIM; d4 += 4) {
      float4 kv = *(const float4*)(&Ks[lane][d4]);
      #pragma unroll
      for (int r = 0; r < 16; ++r) {
        float4 qv = *(const float4*)(&Qs[w * 16 + r][d4]);
        s[r] += qv.x * kv.x + qv.y * kv.y + qv.z * kv.z + qv.w * kv.w;
      }
    }
    // mask: mask==0 -> -1e9 (exactly as reference)
    #pragma unroll
    for (int r = 0; r < 16; ++r) {
      int mm = mbase[(size_t)(w * 16 + r) * S_LEN + k0 + lane];
      if (mm == 0) s[r] = -1.0e9f;
    }

    // ---- online softmax per row ----
    float scale[16];
    #pragma unroll
    for (int r = 0; r < 16; ++r) {
      float tmax = s[r];
      #pragma unroll
      for (int off = 32; off > 0; off >>= 1) tmax = fmaxf(tmax, __shfl_xor(tmax, off));
      float mn = fmaxf(m[r], tmax);
      float p  = __expf(s[r] - mn);
      float ps = p;
      #pragma unroll
      for (int off = 32; off > 0; off >>= 1) ps += __shfl_xor(ps, off);
      scale[r] = __expf(m[r] - mn);
      l[r] = l[r] * scale[r] + ps;
      m[r] = mn;
      Ps[w][r][lane] = p;   // same-wave write; ordered vs reads by lgkmcnt
    }

    // ---- Phase B: PV accumulate, lane = head dim ----
    #pragma unroll
    for (int r = 0; r < 16; ++r) acc[r] *= scale[r];
    for (int j = 0; j < 64; ++j) {
      float vj = Vs[j][lane];
      #pragma unroll
      for (int r = 0; r < 16; ++r) acc[r] += Ps[w][r][j] * vj;
    }
    __syncthreads();  // protect Ks/Vs before next stage
  }

  // epilogue: O[b][q0+w*16+r][h*64 + lane] = acc/l
  #pragma unroll
  for (int r = 0; r < 16; ++r) {
    size_t row = (size_t)b * S_LEN + q0 + w * 16 + r;
    O[row * DMODEL + h * HDIM + lane] = acc[r] / l[r];
  }
}

// ---------------------------------------------------------------------------
extern "C" void kernel_launch(void* const* d_in, const int* in_sizes, int n_in,
                              void* d_out, int out_size, void* d_ws, size_t ws_size,
                              hipStream_t stream) {
  const float* query = (const float*)d_in[0];
  const float* key   = (const float*)d_in[1];
  const float* value = (const float*)d_in[2];
  const int*   mask  = (const int*)  d_in[3];
  const float* Wq = (const float*)d_in[4];
  const float* bq = (const float*)d_in[5];
  const float* Wk = (const float*)d_in[6];
  const float* bk = (const float*)d_in[7];
  const float* Wv = (const float*)d_in[8];
  const float* bv = (const float*)d_in[9];
  const float* Wo = (const float*)d_in[10];
  const float* bo = (const float*)d_in[11];
  float* out = (float*)d_out;

  // workspace: q,k,v in [B,H,S,HD] + attn context [B,S,D] = 4 x 4,194,304 floats = 64 MB
  const size_t NTOK = (size_t)2 * S_LEN;          // 8192
  const size_t PER  = NTOK * DMODEL;              // 4,194,304
  float* qb = (float*)d_ws;
  float* kb = qb + PER;
  float* vb = kb + PER;
  float* ab = vb + PER;

  dim3 gg(NTOK / 64, DMODEL / 64);  // (128, 8)
  gemm_xwt<<<gg, 256, 0, stream>>>(query, Wq, bq, qb, 0);
  gemm_xwt<<<gg, 256, 0, stream>>>(key,   Wk, bk, kb, 0);
  gemm_xwt<<<gg, 256, 0, stream>>>(value, Wv, bv, vb, 0);

  dim3 ga(S_LEN / 64, 2 * NHEAD);   // (64, 16)
  flash_attn<<<ga, 256, 0, stream>>>(qb, kb, vb, mask, ab);

  gemm_xwt<<<gg, 256, 0, stream>>>(ab, Wo, bo, out, 1);
}

// Round 2
// 590.538 us; speedup vs baseline: 5.5063x; 5.5063x over previous
//
#include <hip/hip_runtime.h>
#include <hip/hip_bf16.h>
#include <cstddef>
#include <cstdint>

// MultiHeadAttention: B=2, S=4096, D=512, H=8, HD=64
// Round 2: bf16 MFMA everywhere, hi/lo 2-term split on score path for accuracy.

#define S_LEN 4096
#define DMODEL 512
#define NHEAD 8
#define HDIM 64
#define NWORDS (S_LEN / 64)   // 64-bit mask words per row

typedef __bf16 bf16x8 __attribute__((ext_vector_type(8)));
typedef float f32x4 __attribute__((ext_vector_type(4)));
typedef unsigned short u16x4 __attribute__((ext_vector_type(4)));
typedef unsigned short u16x8 __attribute__((ext_vector_type(8)));

__device__ __forceinline__ unsigned short f2bf(float x) {
  union { float f; unsigned u; } v; v.f = x;
  unsigned r = v.u + 0x7fffu + ((v.u >> 16) & 1u);   // RNE
  return (unsigned short)(r >> 16);
}
__device__ __forceinline__ float bf2f(unsigned short h) {
  union { unsigned u; float f; } v; v.u = ((unsigned)h) << 16; return v.f;
}
// swizzled ushort index into a [*][64] bf16 tile (128B rows, 16B chunk XOR row&7)
__device__ __forceinline__ int swzi(int row, int col) {
  return row * 64 + ((col & 7) | ((((col >> 3) ^ row) & 7) << 3));
}

// ---------------------------------------------------------------------------
// pack mask bits: bit i of word w = (mask[w*64+i] != 0)
// ---------------------------------------------------------------------------
__global__ __launch_bounds__(256) void pack_mask(
    const int* __restrict__ mask, unsigned long long* __restrict__ bits, int nwords)
{
  int gw = (blockIdx.x * blockDim.x + threadIdx.x) >> 6;
  int lane = threadIdx.x & 63;
  int nw = (gridDim.x * blockDim.x) >> 6;
  for (int w = gw; w < nwords; w += nw) {
    int v = mask[(size_t)w * 64 + lane];
    unsigned long long b = __ballot(v != 0);
    if (lane == 0) bits[w] = b;
  }
}

// ---------------------------------------------------------------------------
// GEMM: Y[n][o] = sum_i X[n][i]*W[o][i] + bias[o], hi/lo bf16 3-pass MFMA.
// BM=128, BN=64, BK=64. 4 waves, each 32 rows x 64 cols.
// mode 0: scatter to [B,H,S,HD]; mode 1: flat [N,DMODEL].
// ---------------------------------------------------------------------------
__global__ __launch_bounds__(256) void gemm_mfma(
    const float* __restrict__ X, const float* __restrict__ W,
    const float* __restrict__ bias, float* __restrict__ Y, int mode)
{
  __shared__ __align__(16) unsigned short Xh[128 * 64];
  __shared__ __align__(16) unsigned short Xl[128 * 64];
  __shared__ __align__(16) unsigned short Wh[64 * 64];
  __shared__ __align__(16) unsigned short Wl[64 * 64];

  const int t = threadIdx.x;
  const int lane = t & 63;
  const int w = t >> 6;
  const int c = lane & 15;
  const int g = lane >> 4;
  const int row0 = blockIdx.x * 128;
  const int col0 = blockIdx.y * 64;

  f32x4 acc[2][4];
  #pragma unroll
  for (int mi = 0; mi < 2; ++mi)
    #pragma unroll
    for (int n = 0; n < 4; ++n) acc[mi][n] = (f32x4){0.f, 0.f, 0.f, 0.f};

  for (int k0 = 0; k0 < DMODEL; k0 += 64) {
    // stage X tile 128x64 (f32 -> bf16 hi/lo)
    #pragma unroll
    for (int i = 0; i < 8; ++i) {
      int id = i * 256 + t;
      int r = id >> 4, c4 = (id & 15) << 2;
      float4 f = *(const float4*)(X + (size_t)(row0 + r) * DMODEL + k0 + c4);
      float ff[4] = {f.x, f.y, f.z, f.w};
      u16x4 hh, ll;
      #pragma unroll
      for (int j = 0; j < 4; ++j) { unsigned short hb = f2bf(ff[j]); hh[j] = hb; ll[j] = f2bf(ff[j] - bf2f(hb)); }
      *(u16x4*)&Xh[swzi(r, c4)] = hh;
      *(u16x4*)&Xl[swzi(r, c4)] = ll;
    }
    // stage W tile 64x64
    #pragma unroll
    for (int i = 0; i < 4; ++i) {
      int id = i * 256 + t;
      int r = id >> 4, c4 = (id & 15) << 2;
      float4 f = *(const float4*)(W + (size_t)(col0 + r) * DMODEL + k0 + c4);
      float ff[4] = {f.x, f.y, f.z, f.w};
      u16x4 hh, ll;
      #pragma unroll
      for (int j = 0; j < 4; ++j) { unsigned short hb = f2bf(ff[j]); hh[j] = hb; ll[j] = f2bf(ff[j] - bf2f(hb)); }
      *(u16x4*)&Wh[swzi(r, c4)] = hh;
      *(u16x4*)&Wl[swzi(r, c4)] = ll;
    }
    __syncthreads();

    #pragma unroll
    for (int kk = 0; kk < 2; ++kk) {
      bf16x8 ah[2], al[2], bh_[4], bl_[4];
      #pragma unroll
      for (int mi = 0; mi < 2; ++mi) {
        int r = w * 32 + mi * 16 + c;
        ah[mi] = __builtin_bit_cast(bf16x8, *(const u16x8*)&Xh[swzi(r, (kk * 4 + g) * 8)]);
        al[mi] = __builtin_bit_cast(bf16x8, *(const u16x8*)&Xl[swzi(r, (kk * 4 + g) * 8)]);
      }
      #pragma unroll
      for (int n = 0; n < 4; ++n) {
        int r = n * 16 + c;
        bh_[n] = __builtin_bit_cast(bf16x8, *(const u16x8*)&Wh[swzi(r, (kk * 4 + g) * 8)]);
        bl_[n] = __builtin_bit_cast(bf16x8, *(const u16x8*)&Wl[swzi(r, (kk * 4 + g) * 8)]);
      }
      #pragma unroll
      for (int mi = 0; mi < 2; ++mi)
        #pragma unroll
        for (int n = 0; n < 4; ++n) {
          acc[mi][n] = __builtin_amdgcn_mfma_f32_16x16x32_bf16(ah[mi], bh_[n], acc[mi][n], 0, 0, 0);
          acc[mi][n] = __builtin_amdgcn_mfma_f32_16x16x32_bf16(al[mi], bh_[n], acc[mi][n], 0, 0, 0);
          acc[mi][n] = __builtin_amdgcn_mfma_f32_16x16x32_bf16(ah[mi], bl_[n], acc[mi][n], 0, 0, 0);
        }
    }
    __syncthreads();
  }

  #pragma unroll
  for (int mi = 0; mi < 2; ++mi)
    #pragma unroll
    for (int n = 0; n < 4; ++n)
      #pragma unroll
      for (int j = 0; j < 4; ++j) {
        int rr = row0 + w * 32 + mi * 16 + g * 4 + j;
        int oo = col0 + n * 16 + c;
        float val = acc[mi][n][j] + bias[oo];
        if (mode == 0) {
          int bb = rr >> 12, ss = rr & (S_LEN - 1), hh2 = oo >> 6, hd = oo & 63;
          Y[(((size_t)(bb * NHEAD + hh2)) * S_LEN + ss) * HDIM + hd] = val;
        } else {
          Y[(size_t)rr * DMODEL + oo] = val;
        }
      }
}

// ---------------------------------------------------------------------------
// Flash attention, MFMA. Block = (qtile of 64 rows, b*H+h). 4 waves x 16 rows.
// Scores via 3-pass hi/lo bf16 MFMA; PV single bf16.
// ---------------------------------------------------------------------------
__global__ __launch_bounds__(256) void attn_mfma(
    const float* __restrict__ Q, const float* __restrict__ K, const float* __restrict__ V,
    const unsigned long long* __restrict__ mbits, float* __restrict__ O)
{
  __shared__ __align__(16) unsigned short Kh[64 * 64];
  __shared__ __align__(16) unsigned short Kl[64 * 64];
  __shared__ __align__(16) unsigned short Vt[64 * 64];
  __shared__ __align__(16) unsigned short Ps[4][16 * 64];

  const int t = threadIdx.x;
  const int lane = t & 63;
  const int w = t >> 6;
  const int c = lane & 15;
  const int g = lane >> 4;
  const int q0 = blockIdx.x * 64;
  const int bh = blockIdx.y;
  const int b = bh >> 3;
  const int h = bh & 7;

  // Q fragments (hi/lo), row = c, dims 32*kk + 8*g + [0,8)
  const float* Qr = Q + ((size_t)bh * S_LEN + q0 + w * 16 + c) * HDIM;
  bf16x8 qh[2], ql[2];
  #pragma unroll
  for (int kk = 0; kk < 2; ++kk) {
    float4 f0 = *(const float4*)(Qr + kk * 32 + g * 8);
    float4 f1 = *(const float4*)(Qr + kk * 32 + g * 8 + 4);
    float ff[8] = {f0.x, f0.y, f0.z, f0.w, f1.x, f1.y, f1.z, f1.w};
    u16x8 hh, ll;
    #pragma unroll
    for (int j = 0; j < 8; ++j) { unsigned short hb = f2bf(ff[j]); hh[j] = hb; ll[j] = f2bf(ff[j] - bf2f(hb)); }
    qh[kk] = __builtin_bit_cast(bf16x8, hh);
    ql[kk] = __builtin_bit_cast(bf16x8, ll);
  }

  const float* Kb = K + (size_t)bh * S_LEN * HDIM;
  const float* Vb = V + (size_t)bh * S_LEN * HDIM;

  f32x4 oacc[4];
  #pragma unroll
  for (int n = 0; n < 4; ++n) oacc[n] = (f32x4){0.f, 0.f, 0.f, 0.f};
  float mrow[4], lrow[4];
  #pragma unroll
  for (int j = 0; j < 4; ++j) { mrow[j] = -INFINITY; lrow[j] = 0.f; }

  for (int k0 = 0; k0 < S_LEN; k0 += 64) {
    // ---- stage K (hi/lo) ----
    #pragma unroll
    for (int i = 0; i < 4; ++i) {
      int id = i * 256 + t;
      int r = id >> 4, c4 = (id & 15) << 2;
      float4 f = *(const float4*)(Kb + (size_t)(k0 + r) * HDIM + c4);
      float ff[4] = {f.x, f.y, f.z, f.w};
      u16x4 hh, ll;
      #pragma unroll
      for (int j = 0; j < 4; ++j) { unsigned short hb = f2bf(ff[j]); hh[j] = hb; ll[j] = f2bf(ff[j] - bf2f(hb)); }
      *(u16x4*)&Kh[swzi(r, c4)] = hh;
      *(u16x4*)&Kl[swzi(r, c4)] = ll;
    }
    // ---- stage V transposed: Vt[dim][kv] ----
    {
      int d = t & 63;
      int rg = t >> 6;
      #pragma unroll
      for (int i = 0; i < 4; ++i) {
        int r0 = rg * 16 + i * 4;
        u16x4 hh;
        #pragma unroll
        for (int j = 0; j < 4; ++j) hh[j] = f2bf(Vb[(size_t)(k0 + r0 + j) * HDIM + d]);
        *(u16x4*)&Vt[swzi(d, r0)] = hh;
      }
    }
    __syncthreads();

    // ---- scores: 16(q) x 64(kv), 3-pass hi/lo ----
    f32x4 sf[4];
    #pragma unroll
    for (int n = 0; n < 4; ++n) {
      f32x4 a2 = (f32x4){0.f, 0.f, 0.f, 0.f};
      #pragma unroll
      for (int kk = 0; kk < 2; ++kk) {
        int row = n * 16 + c;
        bf16x8 kh = __builtin_bit_cast(bf16x8, *(const u16x8*)&Kh[swzi(row, (kk * 4 + g) * 8)]);
        bf16x8 kl = __builtin_bit_cast(bf16x8, *(const u16x8*)&Kl[swzi(row, (kk * 4 + g) * 8)]);
        a2 = __builtin_amdgcn_mfma_f32_16x16x32_bf16(qh[kk], kh, a2, 0, 0, 0);
        a2 = __builtin_amdgcn_mfma_f32_16x16x32_bf16(ql[kk], kh, a2, 0, 0, 0);
        a2 = __builtin_amdgcn_mfma_f32_16x16x32_bf16(qh[kk], kl, a2, 0, 0, 0);
      }
      sf[n] = a2;
    }

    // ---- mask + online softmax (rows 4g+j, cols 16n+c) ----
    const int kw = k0 >> 6;
    float scl[4];
    #pragma unroll
    for (int j = 0; j < 4; ++j) {
      unsigned long long m64 = mbits[(size_t)(b * S_LEN + q0 + w * 16 + g * 4 + j) * NWORDS + kw];
      #pragma unroll
      for (int n = 0; n < 4; ++n) {
        bool keep = (m64 >> (n * 16 + c)) & 1ull;
        sf[n][j] = keep ? sf[n][j] : -1.0e9f;
      }
      float mx = fmaxf(fmaxf(sf[0][j], sf[1][j]), fmaxf(sf[2][j], sf[3][j]));
      mx = fmaxf(mx, __shfl_xor(mx, 1));
      mx = fmaxf(mx, __shfl_xor(mx, 2));
      mx = fmaxf(mx, __shfl_xor(mx, 4));
      mx = fmaxf(mx, __shfl_xor(mx, 8));
      float mn = fmaxf(mrow[j], mx);
      scl[j] = __expf(mrow[j] - mn);
      mrow[j] = mn;
      float ps = 0.f;
      #pragma unroll
      for (int n = 0; n < 4; ++n) {
        float p = __expf(sf[n][j] - mn);
        sf[n][j] = p;
        ps += p;
      }
      ps += __shfl_xor(ps, 1);
      ps += __shfl_xor(ps, 2);
      ps += __shfl_xor(ps, 4);
      ps += __shfl_xor(ps, 8);
      lrow[j] = lrow[j] * scl[j] + ps;
    }

    // ---- P -> bf16 LDS (per-wave) ----
    #pragma unroll
    for (int j = 0; j < 4; ++j) {
      int row = g * 4 + j;
      #pragma unroll
      for (int n = 0; n < 4; ++n) Ps[w][swzi(row, n * 16 + c)] = f2bf(sf[n][j]);
    }

    // ---- rescale O, PV MFMA ----
    #pragma unroll
    for (int n = 0; n < 4; ++n)
      #pragma unroll
      for (int j = 0; j < 4; ++j) oacc[n][j] *= scl[j];

    #pragma unroll
    for (int kk = 0; kk < 2; ++kk) {
      bf16x8 pa = __builtin_bit_cast(bf16x8, *(const u16x8*)&Ps[w][swzi(c, (kk * 4 + g) * 8)]);
      #pragma unroll
      for (int n = 0; n < 4; ++n) {
        int row = n * 16 + c;
        bf16x8 vb = __builtin_bit_cast(bf16x8, *(const u16x8*)&Vt[swzi(row, (kk * 4 + g) * 8)]);
        oacc[n] = __builtin_amdgcn_mfma_f32_16x16x32_bf16(pa, vb, oacc[n], 0, 0, 0);
      }
    }
    __syncthreads();
  }

  // epilogue: O[b][q0+w*16+4g+j][h*64 + 16n+c] = oacc/l
  #pragma unroll
  for (int j = 0; j < 4; ++j) {
    float inv = 1.0f / lrow[j];
    size_t row = (size_t)b * S_LEN + q0 + w * 16 + g * 4 + j;
    #pragma unroll
    for (int n = 0; n < 4; ++n) O[row * DMODEL + h * HDIM + n * 16 + c] = oacc[n][j] * inv;
  }
}

// ---------------------------------------------------------------------------
extern "C" void kernel_launch(void* const* d_in, const int* in_sizes, int n_in,
                              void* d_out, int out_size, void* d_ws, size_t ws_size,
                              hipStream_t stream) {
  const float* query = (const float*)d_in[0];
  const float* key   = (const float*)d_in[1];
  const float* value = (const float*)d_in[2];
  const int*   mask  = (const int*)  d_in[3];
  const float* Wq = (const float*)d_in[4];
  const float* bq = (const float*)d_in[5];
  const float* Wk = (const float*)d_in[6];
  const float* bk = (const float*)d_in[7];
  const float* Wv = (const float*)d_in[8];
  const float* bv = (const float*)d_in[9];
  const float* Wo = (const float*)d_in[10];
  const float* bo = (const float*)d_in[11];
  float* out = (float*)d_out;

  const size_t NTOK = (size_t)2 * S_LEN;   // 8192
  const size_t PER  = NTOK * DMODEL;       // 4,194,304 floats
  float* qb = (float*)d_ws;
  float* kb = qb + PER;
  float* vb = kb + PER;
  float* ab = vb + PER;

  // mask bits live in d_out (4 MB of 16 MB); final GEMM overwrites all of d_out.
  unsigned long long* bits = (unsigned long long*)d_out;
  const int nwords = 2 * S_LEN * NWORDS;   // 524288
  pack_mask<<<1024, 256, 0, stream>>>(mask, bits, nwords);

  dim3 gg(NTOK / 128, DMODEL / 64);        // (64, 8)
  gemm_mfma<<<gg, 256, 0, stream>>>(query, Wq, bq, qb, 0);
  gemm_mfma<<<gg, 256, 0, stream>>>(key,   Wk, bk, kb, 0);
  gemm_mfma<<<gg, 256, 0, stream>>>(value, Wv, bv, vb, 0);

  dim3 ga(S_LEN / 64, 2 * NHEAD);          // (64, 16)
  attn_mfma<<<ga, 256, 0, stream>>>(qb, kb, vb, bits, ab);

  gemm_mfma<<<gg, 256, 0, stream>>>(ab, Wo, bo, out, 1);
}

// Round 3
// 543.230 us; speedup vs baseline: 5.9859x; 1.0871x over previous
//
#include <hip/hip_runtime.h>
#include <hip/hip_bf16.h>
#include <cstddef>
#include <cstdint>

// MultiHeadAttention: B=2, S=4096, D=512, H=8, HD=64
// Round 3: projections emit bf16 (Q/K hi+lo, V transposed); attention staging is
// pure vectorized copy. 3-pass hi/lo MFMA on score path, single-pass PV.

#define S_LEN 4096
#define DMODEL 512
#define NHEAD 8
#define HDIM 64
#define NWORDS (S_LEN / 64)

typedef __bf16 bf16x8 __attribute__((ext_vector_type(8)));
typedef float f32x4 __attribute__((ext_vector_type(4)));
typedef unsigned short u16x4 __attribute__((ext_vector_type(4)));
typedef unsigned short u16x8 __attribute__((ext_vector_type(8)));

__device__ __forceinline__ unsigned short f2bf(float x) {
  union { float f; unsigned u; } v; v.f = x;
  unsigned r = v.u + 0x7fffu + ((v.u >> 16) & 1u);   // RNE
  return (unsigned short)(r >> 16);
}
__device__ __forceinline__ float bf2f(unsigned short h) {
  union { unsigned u; float f; } v; v.u = ((unsigned)h) << 16; return v.f;
}
// swizzled ushort index into a [*][64] bf16 tile (128B rows, 16B chunk XOR row&7)
__device__ __forceinline__ int swzi(int row, int col) {
  return row * 64 + ((col & 7) | ((((col >> 3) ^ row) & 7) << 3));
}

// ---------------------------------------------------------------------------
__global__ __launch_bounds__(256) void pack_mask(
    const int* __restrict__ mask, unsigned long long* __restrict__ bits, int nwords)
{
  int gw = (blockIdx.x * blockDim.x + threadIdx.x) >> 6;
  int lane = threadIdx.x & 63;
  int nw = (gridDim.x * blockDim.x) >> 6;
  for (int w = gw; w < nwords; w += nw) {
    int v = mask[(size_t)w * 64 + lane];
    unsigned long long b = __ballot(v != 0);
    if (lane == 0) bits[w] = b;
  }
}

// ---------------------------------------------------------------------------
// GEMM: Y[n][o] = sum_i X[n][i]*W[o][i] + bias[o], hi/lo bf16 MFMA.
// MODE 0: out bf16 hi+lo, head-split [B,H,S,HD]     (Q,K)
// MODE 1: out f32 flat [N,DMODEL]                   (final O-projection)
// MODE 2: out bf16 single, transposed [B,H,HD,S]    (V), single-pass MFMA
// ---------------------------------------------------------------------------
template <int MODE>
__global__ __launch_bounds__(256) void gemm_mfma(
    const float* __restrict__ X, const float* __restrict__ W,
    const float* __restrict__ bias, void* __restrict__ out0, void* __restrict__ out1)
{
  __shared__ __align__(16) unsigned short SMEM[24576];   // 48 KB
  unsigned short* Xh = SMEM;           // 128*64
  unsigned short* Xl = SMEM + 8192;    // 128*64
  unsigned short* Wh = SMEM + 16384;   // 64*64
  unsigned short* Wl = SMEM + 20480;   // 64*64

  const int t = threadIdx.x;
  const int lane = t & 63;
  const int w = t >> 6;
  const int c = lane & 15;
  const int g = lane >> 4;
  const int row0 = blockIdx.x * 128;
  const int col0 = blockIdx.y * 64;

  f32x4 acc[2][4];
  #pragma unroll
  for (int mi = 0; mi < 2; ++mi)
    #pragma unroll
    for (int n = 0; n < 4; ++n) acc[mi][n] = (f32x4){0.f, 0.f, 0.f, 0.f};

  for (int k0 = 0; k0 < DMODEL; k0 += 64) {
    #pragma unroll
    for (int i = 0; i < 8; ++i) {
      int id = i * 256 + t;
      int r = id >> 4, c4 = (id & 15) << 2;
      float4 f = *(const float4*)(X + (size_t)(row0 + r) * DMODEL + k0 + c4);
      float ff[4] = {f.x, f.y, f.z, f.w};
      u16x4 hh, ll;
      #pragma unroll
      for (int j = 0; j < 4; ++j) { unsigned short hb = f2bf(ff[j]); hh[j] = hb; ll[j] = f2bf(ff[j] - bf2f(hb)); }
      *(u16x4*)&Xh[swzi(r, c4)] = hh;
      *(u16x4*)&Xl[swzi(r, c4)] = ll;
    }
    #pragma unroll
    for (int i = 0; i < 4; ++i) {
      int id = i * 256 + t;
      int r = id >> 4, c4 = (id & 15) << 2;
      float4 f = *(const float4*)(W + (size_t)(col0 + r) * DMODEL + k0 + c4);
      float ff[4] = {f.x, f.y, f.z, f.w};
      u16x4 hh, ll;
      #pragma unroll
      for (int j = 0; j < 4; ++j) { unsigned short hb = f2bf(ff[j]); hh[j] = hb; ll[j] = f2bf(ff[j] - bf2f(hb)); }
      *(u16x4*)&Wh[swzi(r, c4)] = hh;
      *(u16x4*)&Wl[swzi(r, c4)] = ll;
    }
    __syncthreads();

    #pragma unroll
    for (int kk = 0; kk < 2; ++kk) {
      bf16x8 ah[2], al[2], bh_[4], bl_[4];
      #pragma unroll
      for (int mi = 0; mi < 2; ++mi) {
        int r = w * 32 + mi * 16 + c;
        ah[mi] = __builtin_bit_cast(bf16x8, *(const u16x8*)&Xh[swzi(r, (kk * 4 + g) * 8)]);
        al[mi] = __builtin_bit_cast(bf16x8, *(const u16x8*)&Xl[swzi(r, (kk * 4 + g) * 8)]);
      }
      #pragma unroll
      for (int n = 0; n < 4; ++n) {
        int r = n * 16 + c;
        bh_[n] = __builtin_bit_cast(bf16x8, *(const u16x8*)&Wh[swzi(r, (kk * 4 + g) * 8)]);
        bl_[n] = __builtin_bit_cast(bf16x8, *(const u16x8*)&Wl[swzi(r, (kk * 4 + g) * 8)]);
      }
      #pragma unroll
      for (int mi = 0; mi < 2; ++mi)
        #pragma unroll
        for (int n = 0; n < 4; ++n) {
          acc[mi][n] = __builtin_amdgcn_mfma_f32_16x16x32_bf16(ah[mi], bh_[n], acc[mi][n], 0, 0, 0);
          if (MODE != 2) {
            acc[mi][n] = __builtin_amdgcn_mfma_f32_16x16x32_bf16(al[mi], bh_[n], acc[mi][n], 0, 0, 0);
            acc[mi][n] = __builtin_amdgcn_mfma_f32_16x16x32_bf16(ah[mi], bl_[n], acc[mi][n], 0, 0, 0);
          }
        }
    }
    __syncthreads();
  }

  if (MODE == 0) {
    unsigned short* Yh = (unsigned short*)out0;
    unsigned short* Yl = (unsigned short*)out1;
    #pragma unroll
    for (int mi = 0; mi < 2; ++mi)
      #pragma unroll
      for (int n = 0; n < 4; ++n)
        #pragma unroll
        for (int j = 0; j < 4; ++j) {
          int rr = row0 + w * 32 + mi * 16 + g * 4 + j;
          int oo = col0 + n * 16 + c;
          float val = acc[mi][n][j] + bias[oo];
          int bb = rr >> 12, ss = rr & (S_LEN - 1), h2 = oo >> 6, hd = oo & 63;
          size_t idx = (((size_t)(bb * NHEAD + h2)) * S_LEN + ss) * HDIM + hd;
          unsigned short hb = f2bf(val);
          Yh[idx] = hb;
          Yl[idx] = f2bf(val - bf2f(hb));
        }
  } else if (MODE == 1) {
    float* Y = (float*)out0;
    #pragma unroll
    for (int mi = 0; mi < 2; ++mi)
      #pragma unroll
      for (int n = 0; n < 4; ++n)
        #pragma unroll
        for (int j = 0; j < 4; ++j) {
          int rr = row0 + w * 32 + mi * 16 + g * 4 + j;
          int oo = col0 + n * 16 + c;
          Y[(size_t)rr * DMODEL + oo] = acc[mi][n][j] + bias[oo];
        }
  } else {
    // MODE 2: transpose via LDS, write bf16 [B,H,HD,S]
    unsigned short* Ts = SMEM;   // [128][68]
    #pragma unroll
    for (int mi = 0; mi < 2; ++mi)
      #pragma unroll
      for (int n = 0; n < 4; ++n)
        #pragma unroll
        for (int j = 0; j < 4; ++j) {
          int r = w * 32 + mi * 16 + g * 4 + j;
          int o = n * 16 + c;
          Ts[r * 68 + o] = f2bf(acc[mi][n][j] + bias[col0 + o]);
        }
    __syncthreads();
    unsigned short* vt = (unsigned short*)out0;
    int bb = row0 >> 12, sbase = row0 & (S_LEN - 1), h2 = col0 >> 6;
    int d = t >> 2, s0 = (t & 3) * 32;
    size_t obase = ((size_t)((bb * NHEAD + h2) * HDIM + d)) * S_LEN + sbase + s0;
    #pragma unroll
    for (int i = 0; i < 4; ++i) {
      u16x8 v;
      #pragma unroll
      for (int jj = 0; jj < 8; ++jj) v[jj] = Ts[(s0 + i * 8 + jj) * 68 + d];
      *(u16x8*)(vt + obase + i * 8) = v;
    }
  }
}

// ---------------------------------------------------------------------------
// Flash attention, MFMA, bf16 inputs prepped by projections.
// ---------------------------------------------------------------------------
__global__ __launch_bounds__(256) void attn_mfma(
    const unsigned short* __restrict__ qh, const unsigned short* __restrict__ ql,
    const unsigned short* __restrict__ kh, const unsigned short* __restrict__ kl,
    const unsigned short* __restrict__ vt, const unsigned long long* __restrict__ mbits,
    float* __restrict__ O)
{
  __shared__ __align__(16) unsigned short Kh[4096];
  __shared__ __align__(16) unsigned short Kl[4096];
  __shared__ __align__(16) unsigned short Vt[4096];
  __shared__ __align__(16) unsigned short Ps[4][1024];

  const int t = threadIdx.x;
  const int lane = t & 63;
  const int w = t >> 6;
  const int c = lane & 15;
  const int g = lane >> 4;
  const int q0 = blockIdx.x * 64;
  const int bh = blockIdx.y;
  const int b = bh >> 3;
  const int h = bh & 7;

  // Q fragments straight from global bf16
  const unsigned short* Qhp = qh + ((size_t)bh * S_LEN + q0 + w * 16 + c) * HDIM;
  const unsigned short* Qlp = ql + ((size_t)bh * S_LEN + q0 + w * 16 + c) * HDIM;
  bf16x8 qhf[2], qlf[2];
  #pragma unroll
  for (int kk = 0; kk < 2; ++kk) {
    qhf[kk] = __builtin_bit_cast(bf16x8, *(const u16x8*)(Qhp + kk * 32 + g * 8));
    qlf[kk] = __builtin_bit_cast(bf16x8, *(const u16x8*)(Qlp + kk * 32 + g * 8));
  }

  const unsigned short* Kbh = kh + (size_t)bh * S_LEN * HDIM;
  const unsigned short* Kbl = kl + (size_t)bh * S_LEN * HDIM;
  const unsigned short* Vbt = vt + (size_t)bh * HDIM * S_LEN;

  f32x4 oacc[4];
  #pragma unroll
  for (int n = 0; n < 4; ++n) oacc[n] = (f32x4){0.f, 0.f, 0.f, 0.f};
  float mrow[4], lrow[4];
  #pragma unroll
  for (int j = 0; j < 4; ++j) { mrow[j] = -INFINITY; lrow[j] = 0.f; }

  for (int k0 = 0; k0 < S_LEN; k0 += 64) {
    // ---- stage K hi/lo + Vt: pure 16B copies, swizzled dest ----
    #pragma unroll
    for (int i = 0; i < 2; ++i) {
      int id = i * 256 + t;
      int r = id >> 3, ch = id & 7;
      int dst = r * 64 + ((ch ^ r) & 7) * 8;
      *(u16x8*)&Kh[dst] = *(const u16x8*)(Kbh + (size_t)(k0 + r) * HDIM + ch * 8);
      *(u16x8*)&Kl[dst] = *(const u16x8*)(Kbl + (size_t)(k0 + r) * HDIM + ch * 8);
      *(u16x8*)&Vt[dst] = *(const u16x8*)(Vbt + (size_t)r * S_LEN + k0 + ch * 8);
    }
    __syncthreads();

    // ---- scores: 16(q) x 64(kv), 3-pass hi/lo ----
    f32x4 sf[4];
    #pragma unroll
    for (int n = 0; n < 4; ++n) {
      f32x4 a2 = (f32x4){0.f, 0.f, 0.f, 0.f};
      #pragma unroll
      for (int kk = 0; kk < 2; ++kk) {
        int row = n * 16 + c;
        bf16x8 khf = __builtin_bit_cast(bf16x8, *(const u16x8*)&Kh[swzi(row, (kk * 4 + g) * 8)]);
        bf16x8 klf = __builtin_bit_cast(bf16x8, *(const u16x8*)&Kl[swzi(row, (kk * 4 + g) * 8)]);
        a2 = __builtin_amdgcn_mfma_f32_16x16x32_bf16(qhf[kk], khf, a2, 0, 0, 0);
        a2 = __builtin_amdgcn_mfma_f32_16x16x32_bf16(qlf[kk], khf, a2, 0, 0, 0);
        a2 = __builtin_amdgcn_mfma_f32_16x16x32_bf16(qhf[kk], klf, a2, 0, 0, 0);
      }
      sf[n] = a2;
    }

    // ---- mask + online softmax (rows 4g+j, cols 16n+c) ----
    const int kw = k0 >> 6;
    float scl[4];
    #pragma unroll
    for (int j = 0; j < 4; ++j) {
      unsigned long long m64 = mbits[(size_t)(b * S_LEN + q0 + w * 16 + g * 4 + j) * NWORDS + kw];
      #pragma unroll
      for (int n = 0; n < 4; ++n) {
        bool keep = (m64 >> (n * 16 + c)) & 1ull;
        sf[n][j] = keep ? sf[n][j] : -1.0e9f;
      }
      float mx = fmaxf(fmaxf(sf[0][j], sf[1][j]), fmaxf(sf[2][j], sf[3][j]));
      mx = fmaxf(mx, __shfl_xor(mx, 1));
      mx = fmaxf(mx, __shfl_xor(mx, 2));
      mx = fmaxf(mx, __shfl_xor(mx, 4));
      mx = fmaxf(mx, __shfl_xor(mx, 8));
      float mn = fmaxf(mrow[j], mx);
      scl[j] = __expf(mrow[j] - mn);
      mrow[j] = mn;
      float ps = 0.f;
      #pragma unroll
      for (int n = 0; n < 4; ++n) {
        float p = __expf(sf[n][j] - mn);
        sf[n][j] = p;
        ps += p;
      }
      ps += __shfl_xor(ps, 1);
      ps += __shfl_xor(ps, 2);
      ps += __shfl_xor(ps, 4);
      ps += __shfl_xor(ps, 8);
      lrow[j] = lrow[j] * scl[j] + ps;
    }

    // ---- P -> bf16 LDS (per-wave) ----
    #pragma unroll
    for (int j = 0; j < 4; ++j) {
      int row = g * 4 + j;
      #pragma unroll
      for (int n = 0; n < 4; ++n) Ps[w][swzi(row, n * 16 + c)] = f2bf(sf[n][j]);
    }

    // ---- rescale O, PV MFMA ----
    #pragma unroll
    for (int n = 0; n < 4; ++n)
      #pragma unroll
      for (int j = 0; j < 4; ++j) oacc[n][j] *= scl[j];

    #pragma unroll
    for (int kk = 0; kk < 2; ++kk) {
      bf16x8 pa = __builtin_bit_cast(bf16x8, *(const u16x8*)&Ps[w][swzi(c, (kk * 4 + g) * 8)]);
      #pragma unroll
      for (int n = 0; n < 4; ++n) {
        int row = n * 16 + c;
        bf16x8 vbf = __builtin_bit_cast(bf16x8, *(const u16x8*)&Vt[swzi(row, (kk * 4 + g) * 8)]);
        oacc[n] = __builtin_amdgcn_mfma_f32_16x16x32_bf16(pa, vbf, oacc[n], 0, 0, 0);
      }
    }
    __syncthreads();
  }

  #pragma unroll
  for (int j = 0; j < 4; ++j) {
    float inv = 1.0f / lrow[j];
    size_t row = (size_t)b * S_LEN + q0 + w * 16 + g * 4 + j;
    #pragma unroll
    for (int n = 0; n < 4; ++n) O[row * DMODEL + h * HDIM + n * 16 + c] = oacc[n][j] * inv;
  }
}

// ---------------------------------------------------------------------------
extern "C" void kernel_launch(void* const* d_in, const int* in_sizes, int n_in,
                              void* d_out, int out_size, void* d_ws, size_t ws_size,
                              hipStream_t stream) {
  const float* query = (const float*)d_in[0];
  const float* key   = (const float*)d_in[1];
  const float* value = (const float*)d_in[2];
  const int*   mask  = (const int*)  d_in[3];
  const float* Wq = (const float*)d_in[4];
  const float* bq = (const float*)d_in[5];
  const float* Wk = (const float*)d_in[6];
  const float* bk = (const float*)d_in[7];
  const float* Wv = (const float*)d_in[8];
  const float* bv = (const float*)d_in[9];
  const float* Wo = (const float*)d_in[10];
  const float* bo = (const float*)d_in[11];
  float* out = (float*)d_out;

  const size_t NTOK = (size_t)2 * S_LEN;           // 8192
  const size_t PER  = NTOK * DMODEL;               // 4,194,304 elements
  unsigned short* qhb = (unsigned short*)d_ws;     // 8 MB each
  unsigned short* qlb = qhb + PER;
  unsigned short* khb = qlb + PER;
  unsigned short* klb = khb + PER;
  unsigned short* vtb = klb + PER;
  float* ab = (float*)(vtb + PER);                 // 16 MB

  unsigned long long* bits = (unsigned long long*)d_out;   // 4 MB, overwritten by final GEMM
  const int nwords = 2 * S_LEN * NWORDS;
  pack_mask<<<1024, 256, 0, stream>>>(mask, bits, nwords);

  dim3 gg(NTOK / 128, DMODEL / 64);                // (64, 8)
  gemm_mfma<0><<<gg, 256, 0, stream>>>(query, Wq, bq, qhb, qlb);
  gemm_mfma<0><<<gg, 256, 0, stream>>>(key,   Wk, bk, khb, klb);
  gemm_mfma<2><<<gg, 256, 0, stream>>>(value, Wv, bv, vtb, nullptr);

  dim3 ga(S_LEN / 64, 2 * NHEAD);                  // (64, 16)
  attn_mfma<<<ga, 256, 0, stream>>>(qhb, qlb, khb, klb, vtb, bits, ab);

  gemm_mfma<1><<<gg, 256, 0, stream>>>(ab, Wo, bo, out, nullptr);
}

// Round 4
// 439.162 us; speedup vs baseline: 7.4043x; 1.2370x over previous
//
#include <hip/hip_runtime.h>
#include <hip/hip_bf16.h>
#include <cstddef>
#include <cstdint>

// MultiHeadAttention: B=2, S=4096, D=512, H=8, HD=64
// Round 4: 8-wave attn blocks (QBLK=128) + T14 async staging split + pre-converted
// bf16 hi/lo inputs for all GEMMs; (__bf16) casts instead of manual bit-RNE.

#define S_LEN 4096
#define DMODEL 512
#define NHEAD 8
#define HDIM 64
#define NWORDS (S_LEN / 64)

typedef __bf16 bf16x8 __attribute__((ext_vector_type(8)));
typedef float f32x4 __attribute__((ext_vector_type(4)));
typedef unsigned short u16x4 __attribute__((ext_vector_type(4)));
typedef unsigned short u16x8 __attribute__((ext_vector_type(8)));

__device__ __forceinline__ unsigned short f2bf(float x) {
  return __builtin_bit_cast(unsigned short, (__bf16)x);
}
__device__ __forceinline__ float bf2f(unsigned short h) {
  union { unsigned u; float f; } v; v.u = ((unsigned)h) << 16; return v.f;
}
// swizzled ushort index into a [*][64] bf16 tile (128B rows, 16B chunk XOR row&7)
__device__ __forceinline__ int swzi(int row, int col) {
  return row * 64 + ((col & 7) | ((((col >> 3) ^ row) & 7) << 3));
}

// ---------------------------------------------------------------------------
__global__ __launch_bounds__(256) void pack_mask(
    const int* __restrict__ mask, unsigned long long* __restrict__ bits, int nwords)
{
  int gw = (blockIdx.x * blockDim.x + threadIdx.x) >> 6;
  int lane = threadIdx.x & 63;
  int nw = (gridDim.x * blockDim.x) >> 6;
  for (int w = gw; w < nwords; w += nw) {
    int v = mask[(size_t)w * 64 + lane];
    unsigned long long b = __ballot(v != 0);
    if (lane == 0) bits[w] = b;
  }
}

// ---------------------------------------------------------------------------
// f32 -> bf16 hi/lo split, flat
// ---------------------------------------------------------------------------
__global__ __launch_bounds__(256) void conv_hilo(
    const float* __restrict__ x, unsigned short* __restrict__ h,
    unsigned short* __restrict__ l, int n4)
{
  int i = blockIdx.x * 256 + threadIdx.x;
  int stride = gridDim.x * 256;
  for (; i < n4; i += stride) {
    float4 f = ((const float4*)x)[i];
    float ff[4] = {f.x, f.y, f.z, f.w};
    u16x4 hh, ll;
    #pragma unroll
    for (int j = 0; j < 4; ++j) {
      unsigned short hb = f2bf(ff[j]);
      hh[j] = hb;
      ll[j] = f2bf(ff[j] - bf2f(hb));
    }
    ((u16x4*)h)[i] = hh;
    ((u16x4*)l)[i] = ll;
  }
}

// all four weight matrices in one launch: y-dim picks the weight
__global__ __launch_bounds__(256) void conv_w4(
    const float* __restrict__ w0, const float* __restrict__ w1,
    const float* __restrict__ w2, const float* __restrict__ w3,
    unsigned short* __restrict__ out)   // [4][2][262144]
{
  const float* src = (blockIdx.y == 0) ? w0 : (blockIdx.y == 1) ? w1 : (blockIdx.y == 2) ? w2 : w3;
  unsigned short* h = out + (size_t)blockIdx.y * 2 * 262144;
  unsigned short* l = h + 262144;
  int i = blockIdx.x * 256 + threadIdx.x;   // 65536 f32x4 per weight
  float4 f = ((const float4*)src)[i];
  float ff[4] = {f.x, f.y, f.z, f.w};
  u16x4 hh, ll;
  #pragma unroll
  for (int j = 0; j < 4; ++j) {
    unsigned short hb = f2bf(ff[j]);
    hh[j] = hb;
    ll[j] = f2bf(ff[j] - bf2f(hb));
  }
  ((u16x4*)h)[i] = hh;
  ((u16x4*)l)[i] = ll;
}

// ---------------------------------------------------------------------------
// GEMM from pre-converted bf16 hi/lo: Y[n][o] = sum_i X[n][i]*W[o][i] + bias[o]
// MODE 0: 3-pass, out bf16 hi+lo head-split [B,H,S,HD]   (Q,K)
// MODE 1: 3-pass, out f32 flat [N,DMODEL]                (final projection)
// MODE 2: 1-pass, out bf16 transposed [B,H,HD,S]         (V)
// BM=128, BN=64, BK=64; 4 waves. T14 prefetch pipeline.
// ---------------------------------------------------------------------------
template <int MODE>
__global__ __launch_bounds__(256) void gemm_pre(
    const unsigned short* __restrict__ xh, const unsigned short* __restrict__ xl,
    const unsigned short* __restrict__ wh, const unsigned short* __restrict__ wl,
    const float* __restrict__ bias, void* __restrict__ out0, void* __restrict__ out1)
{
  __shared__ __align__(16) unsigned short SMEM[24576];   // 48 KB
  unsigned short* Xh = SMEM;           // 128*64
  unsigned short* Xl = SMEM + 8192;
  unsigned short* Wh = SMEM + 16384;   // 64*64
  unsigned short* Wl = SMEM + 20480;

  const int t = threadIdx.x;
  const int lane = t & 63;
  const int w = t >> 6;
  const int c = lane & 15;
  const int g = lane >> 4;
  const int row0 = blockIdx.x * 128;
  const int col0 = blockIdx.y * 64;

  f32x4 acc[2][4];
  #pragma unroll
  for (int mi = 0; mi < 2; ++mi)
    #pragma unroll
    for (int n = 0; n < 4; ++n) acc[mi][n] = (f32x4){0.f, 0.f, 0.f, 0.f};

  // staging assignment: X: 4 chunks/thread/array, W: 2 chunks/thread/array
  u16x8 pxh[4], pxl[4], pwh[2], pwl[2];
  auto issue = [&](int k0) {
    #pragma unroll
    for (int i = 0; i < 4; ++i) {
      int id = i * 256 + t;
      int r = id >> 3, ch = id & 7;
      size_t off = (size_t)(row0 + r) * DMODEL + k0 + ch * 8;
      pxh[i] = *(const u16x8*)(xh + off);
      if (MODE != 2) pxl[i] = *(const u16x8*)(xl + off);
    }
    #pragma unroll
    for (int i = 0; i < 2; ++i) {
      int id = i * 256 + t;
      int r = id >> 3, ch = id & 7;
      size_t off = (size_t)(col0 + r) * DMODEL + k0 + ch * 8;
      pwh[i] = *(const u16x8*)(wh + off);
      if (MODE != 2) pwl[i] = *(const u16x8*)(wl + off);
    }
  };
  auto commit = [&]() {
    #pragma unroll
    for (int i = 0; i < 4; ++i) {
      int id = i * 256 + t;
      int r = id >> 3, ch = id & 7;
      int dst = r * 64 + (((ch ^ r) & 7) << 3);
      *(u16x8*)&Xh[dst] = pxh[i];
      if (MODE != 2) *(u16x8*)&Xl[dst] = pxl[i];
    }
    #pragma unroll
    for (int i = 0; i < 2; ++i) {
      int id = i * 256 + t;
      int r = id >> 3, ch = id & 7;
      int dst = r * 64 + (((ch ^ r) & 7) << 3);
      *(u16x8*)&Wh[dst] = pwh[i];
      if (MODE != 2) *(u16x8*)&Wl[dst] = pwl[i];
    }
  };

  issue(0);
  commit();
  __syncthreads();

  for (int k0 = 0; k0 < DMODEL; k0 += 64) {
    const bool more = (k0 + 64) < DMODEL;
    if (more) issue(k0 + 64);

    #pragma unroll
    for (int kk = 0; kk < 2; ++kk) {
      bf16x8 ah[2], al[2], bh_[4], bl_[4];
      #pragma unroll
      for (int mi = 0; mi < 2; ++mi) {
        int r = w * 32 + mi * 16 + c;
        ah[mi] = __builtin_bit_cast(bf16x8, *(const u16x8*)&Xh[swzi(r, (kk * 4 + g) * 8)]);
        if (MODE != 2) al[mi] = __builtin_bit_cast(bf16x8, *(const u16x8*)&Xl[swzi(r, (kk * 4 + g) * 8)]);
      }
      #pragma unroll
      for (int n = 0; n < 4; ++n) {
        int r = n * 16 + c;
        bh_[n] = __builtin_bit_cast(bf16x8, *(const u16x8*)&Wh[swzi(r, (kk * 4 + g) * 8)]);
        if (MODE != 2) bl_[n] = __builtin_bit_cast(bf16x8, *(const u16x8*)&Wl[swzi(r, (kk * 4 + g) * 8)]);
      }
      #pragma unroll
      for (int mi = 0; mi < 2; ++mi)
        #pragma unroll
        for (int n = 0; n < 4; ++n) {
          acc[mi][n] = __builtin_amdgcn_mfma_f32_16x16x32_bf16(ah[mi], bh_[n], acc[mi][n], 0, 0, 0);
          if (MODE != 2) {
            acc[mi][n] = __builtin_amdgcn_mfma_f32_16x16x32_bf16(al[mi], bh_[n], acc[mi][n], 0, 0, 0);
            acc[mi][n] = __builtin_amdgcn_mfma_f32_16x16x32_bf16(ah[mi], bl_[n], acc[mi][n], 0, 0, 0);
          }
        }
    }
    __syncthreads();
    if (more) {
      commit();
      __syncthreads();
    }
  }

  if (MODE == 0) {
    unsigned short* Yh = (unsigned short*)out0;
    unsigned short* Yl = (unsigned short*)out1;
    #pragma unroll
    for (int mi = 0; mi < 2; ++mi)
      #pragma unroll
      for (int n = 0; n < 4; ++n)
        #pragma unroll
        for (int j = 0; j < 4; ++j) {
          int rr = row0 + w * 32 + mi * 16 + g * 4 + j;
          int oo = col0 + n * 16 + c;
          float val = acc[mi][n][j] + bias[oo];
          int bb = rr >> 12, ss = rr & (S_LEN - 1), h2 = oo >> 6, hd = oo & 63;
          size_t idx = (((size_t)(bb * NHEAD + h2)) * S_LEN + ss) * HDIM + hd;
          unsigned short hb = f2bf(val);
          Yh[idx] = hb;
          Yl[idx] = f2bf(val - bf2f(hb));
        }
  } else if (MODE == 1) {
    float* Y = (float*)out0;
    #pragma unroll
    for (int mi = 0; mi < 2; ++mi)
      #pragma unroll
      for (int n = 0; n < 4; ++n)
        #pragma unroll
        for (int j = 0; j < 4; ++j) {
          int rr = row0 + w * 32 + mi * 16 + g * 4 + j;
          int oo = col0 + n * 16 + c;
          Y[(size_t)rr * DMODEL + oo] = acc[mi][n][j] + bias[oo];
        }
  } else {
    // MODE 2: transpose via LDS, write bf16 [B,H,HD,S]
    unsigned short* Ts = SMEM;   // [128][68]
    #pragma unroll
    for (int mi = 0; mi < 2; ++mi)
      #pragma unroll
      for (int n = 0; n < 4; ++n)
        #pragma unroll
        for (int j = 0; j < 4; ++j) {
          int r = w * 32 + mi * 16 + g * 4 + j;
          int o = n * 16 + c;
          Ts[r * 68 + o] = f2bf(acc[mi][n][j] + bias[col0 + o]);
        }
    __syncthreads();
    unsigned short* vt = (unsigned short*)out0;
    int bb = row0 >> 12, sbase = row0 & (S_LEN - 1), h2 = col0 >> 6;
    int d = t >> 2, s0 = (t & 3) * 32;
    size_t obase = ((size_t)((bb * NHEAD + h2) * HDIM + d)) * S_LEN + sbase + s0;
    #pragma unroll
    for (int i = 0; i < 4; ++i) {
      u16x8 v;
      #pragma unroll
      for (int jj = 0; jj < 8; ++jj) v[jj] = Ts[(s0 + i * 8 + jj) * 68 + d];
      *(u16x8*)(vt + obase + i * 8) = v;
    }
  }
}

// ---------------------------------------------------------------------------
// Flash attention: QBLK=128, 8 waves, T14 prefetch. Output bf16 hi/lo flat.
// ---------------------------------------------------------------------------
__global__ __launch_bounds__(512) void attn_mfma(
    const unsigned short* __restrict__ qh, const unsigned short* __restrict__ ql,
    const unsigned short* __restrict__ kh, const unsigned short* __restrict__ kl,
    const unsigned short* __restrict__ vt, const unsigned long long* __restrict__ mbits,
    unsigned short* __restrict__ Oh, unsigned short* __restrict__ Ol)
{
  __shared__ __align__(16) unsigned short Khs[4096];
  __shared__ __align__(16) unsigned short Kls[4096];
  __shared__ __align__(16) unsigned short Vts[4096];
  __shared__ __align__(16) unsigned short Ps[8][1024];

  const int t = threadIdx.x;
  const int lane = t & 63;
  const int w = t >> 6;          // 0..7
  const int c = lane & 15;
  const int g = lane >> 4;
  const int q0 = blockIdx.x * 128;
  const int bh = blockIdx.y;
  const int b = bh >> 3;
  const int h = bh & 7;

  // Q fragments (rows q0 + w*16 + c)
  const unsigned short* Qhp = qh + ((size_t)bh * S_LEN + q0 + w * 16 + c) * HDIM;
  const unsigned short* Qlp = ql + ((size_t)bh * S_LEN + q0 + w * 16 + c) * HDIM;
  bf16x8 qhf[2], qlf[2];
  #pragma unroll
  for (int kk = 0; kk < 2; ++kk) {
    qhf[kk] = __builtin_bit_cast(bf16x8, *(const u16x8*)(Qhp + kk * 32 + g * 8));
    qlf[kk] = __builtin_bit_cast(bf16x8, *(const u16x8*)(Qlp + kk * 32 + g * 8));
  }

  const unsigned short* Kbh = kh + (size_t)bh * S_LEN * HDIM;
  const unsigned short* Kbl = kl + (size_t)bh * S_LEN * HDIM;
  const unsigned short* Vbt = vt + (size_t)bh * HDIM * S_LEN;

  // staging: 512 threads cover 64 rows x 8 chunks, one u16x8 per array each
  const int sr = t >> 3, sch = t & 7;
  const int sdst = sr * 64 + (((sch ^ sr) & 7) << 3);
  u16x8 pk_h, pk_l, pk_v;
  auto issue = [&](int k0) {
    pk_h = *(const u16x8*)(Kbh + (size_t)(k0 + sr) * HDIM + sch * 8);
    pk_l = *(const u16x8*)(Kbl + (size_t)(k0 + sr) * HDIM + sch * 8);
    pk_v = *(const u16x8*)(Vbt + (size_t)sr * S_LEN + k0 + sch * 8);
  };
  auto commit = [&]() {
    *(u16x8*)&Khs[sdst] = pk_h;
    *(u16x8*)&Kls[sdst] = pk_l;
    *(u16x8*)&Vts[sdst] = pk_v;
  };

  f32x4 oacc[4];
  #pragma unroll
  for (int n = 0; n < 4; ++n) oacc[n] = (f32x4){0.f, 0.f, 0.f, 0.f};
  float mrow[4], lrow[4];
  #pragma unroll
  for (int j = 0; j < 4; ++j) { mrow[j] = -INFINITY; lrow[j] = 0.f; }

  issue(0);
  commit();
  __syncthreads();

  for (int k0 = 0; k0 < S_LEN; k0 += 64) {
    const bool more = (k0 + 64) < S_LEN;
    if (more) issue(k0 + 64);

    // ---- scores: 16(q) x 64(kv), 3-pass hi/lo ----
    f32x4 sf[4];
    #pragma unroll
    for (int n = 0; n < 4; ++n) {
      f32x4 a2 = (f32x4){0.f, 0.f, 0.f, 0.f};
      #pragma unroll
      for (int kk = 0; kk < 2; ++kk) {
        int row = n * 16 + c;
        bf16x8 khf = __builtin_bit_cast(bf16x8, *(const u16x8*)&Khs[swzi(row, (kk * 4 + g) * 8)]);
        bf16x8 klf = __builtin_bit_cast(bf16x8, *(const u16x8*)&Kls[swzi(row, (kk * 4 + g) * 8)]);
        a2 = __builtin_amdgcn_mfma_f32_16x16x32_bf16(qhf[kk], khf, a2, 0, 0, 0);
        a2 = __builtin_amdgcn_mfma_f32_16x16x32_bf16(qlf[kk], khf, a2, 0, 0, 0);
        a2 = __builtin_amdgcn_mfma_f32_16x16x32_bf16(qhf[kk], klf, a2, 0, 0, 0);
      }
      sf[n] = a2;
    }

    // ---- mask + online softmax (rows 4g+j, cols 16n+c) ----
    const int kw = k0 >> 6;
    float scl[4];
    #pragma unroll
    for (int j = 0; j < 4; ++j) {
      unsigned long long m64 = mbits[(size_t)(b * S_LEN + q0 + w * 16 + g * 4 + j) * NWORDS + kw];
      #pragma unroll
      for (int n = 0; n < 4; ++n) {
        bool keep = (m64 >> (n * 16 + c)) & 1ull;
        sf[n][j] = keep ? sf[n][j] : -1.0e9f;
      }
      float mx = fmaxf(fmaxf(sf[0][j], sf[1][j]), fmaxf(sf[2][j], sf[3][j]));
      mx = fmaxf(mx, __shfl_xor(mx, 1));
      mx = fmaxf(mx, __shfl_xor(mx, 2));
      mx = fmaxf(mx, __shfl_xor(mx, 4));
      mx = fmaxf(mx, __shfl_xor(mx, 8));
      float mn = fmaxf(mrow[j], mx);
      scl[j] = __expf(mrow[j] - mn);
      mrow[j] = mn;
      float ps = 0.f;
      #pragma unroll
      for (int n = 0; n < 4; ++n) {
        float p = __expf(sf[n][j] - mn);
        sf[n][j] = p;
        ps += p;
      }
      ps += __shfl_xor(ps, 1);
      ps += __shfl_xor(ps, 2);
      ps += __shfl_xor(ps, 4);
      ps += __shfl_xor(ps, 8);
      lrow[j] = lrow[j] * scl[j] + ps;
    }

    // ---- P -> bf16 LDS (per-wave) ----
    #pragma unroll
    for (int j = 0; j < 4; ++j) {
      int row = g * 4 + j;
      #pragma unroll
      for (int n = 0; n < 4; ++n) Ps[w][swzi(row, n * 16 + c)] = f2bf(sf[n][j]);
    }

    // ---- rescale O, PV MFMA ----
    #pragma unroll
    for (int n = 0; n < 4; ++n)
      #pragma unroll
      for (int j = 0; j < 4; ++j) oacc[n][j] *= scl[j];

    #pragma unroll
    for (int kk = 0; kk < 2; ++kk) {
      bf16x8 pa = __builtin_bit_cast(bf16x8, *(const u16x8*)&Ps[w][swzi(c, (kk * 4 + g) * 8)]);
      #pragma unroll
      for (int n = 0; n < 4; ++n) {
        int row = n * 16 + c;
        bf16x8 vbf = __builtin_bit_cast(bf16x8, *(const u16x8*)&Vts[swzi(row, (kk * 4 + g) * 8)]);
        oacc[n] = __builtin_amdgcn_mfma_f32_16x16x32_bf16(pa, vbf, oacc[n], 0, 0, 0);
      }
    }

    __syncthreads();
    if (more) {
      commit();
      __syncthreads();
    }
  }

  // epilogue: bf16 hi/lo, flat [B*S][DMODEL]
  #pragma unroll
  for (int j = 0; j < 4; ++j) {
    float inv = 1.0f / lrow[j];
    size_t row = (size_t)b * S_LEN + q0 + w * 16 + g * 4 + j;
    #pragma unroll
    for (int n = 0; n < 4; ++n) {
      float val = oacc[n][j] * inv;
      size_t idx = row * DMODEL + h * HDIM + n * 16 + c;
      unsigned short hb = f2bf(val);
      Oh[idx] = hb;
      Ol[idx] = f2bf(val - bf2f(hb));
    }
  }
}

// ---------------------------------------------------------------------------
extern "C" void kernel_launch(void* const* d_in, const int* in_sizes, int n_in,
                              void* d_out, int out_size, void* d_ws, size_t ws_size,
                              hipStream_t stream) {
  const float* query = (const float*)d_in[0];
  const float* key   = (const float*)d_in[1];
  const float* value = (const float*)d_in[2];
  const int*   mask  = (const int*)  d_in[3];
  const float* Wq = (const float*)d_in[4];
  const float* bq = (const float*)d_in[5];
  const float* Wk = (const float*)d_in[6];
  const float* bk = (const float*)d_in[7];
  const float* Wv = (const float*)d_in[8];
  const float* bv = (const float*)d_in[9];
  const float* Wo = (const float*)d_in[10];
  const float* bo = (const float*)d_in[11];
  float* out = (float*)d_out;

  const size_t PER = (size_t)2 * S_LEN * DMODEL;   // 4,194,304 elements
  const size_t WSZ = (size_t)DMODEL * DMODEL;      // 262,144

  unsigned short* p = (unsigned short*)d_ws;
  unsigned short* wbuf = p;                        // [4][2][WSZ] = 4 MB
  unsigned short* xh = p + 8 * WSZ;                // 8 MB
  unsigned short* xl = xh + PER;                   // 8 MB
  unsigned short* qhb = xl + PER;                  // 8 MB
  unsigned short* qlb = qhb + PER;
  unsigned short* khb = qlb + PER;
  unsigned short* klb = khb + PER;
  unsigned short* vtb = klb + PER;                 // total 60 MB

  unsigned short* wqh = wbuf + 0 * 2 * WSZ, *wql = wqh + WSZ;
  unsigned short* wkh = wbuf + 1 * 2 * WSZ, *wkl = wkh + WSZ;
  unsigned short* wvh = wbuf + 2 * 2 * WSZ, *wvl = wvh + WSZ;
  unsigned short* woh = wbuf + 3 * 2 * WSZ, *wol = woh + WSZ;

  unsigned long long* bits = (unsigned long long*)d_out;   // 4 MB of d_out, overwritten by final GEMM
  pack_mask<<<2048, 256, 0, stream>>>(mask, bits, 2 * S_LEN * NWORDS);
  conv_w4<<<dim3(256, 4), 256, 0, stream>>>(Wq, Wk, Wv, Wo, wbuf);

  dim3 gg(2 * S_LEN / 128, DMODEL / 64);           // (64, 8)
  const int N4 = (int)(PER / 4);

  conv_hilo<<<2048, 256, 0, stream>>>(query, xh, xl, N4);
  gemm_pre<0><<<gg, 256, 0, stream>>>(xh, xl, wqh, wql, bq, qhb, qlb);

  conv_hilo<<<2048, 256, 0, stream>>>(key, xh, xl, N4);
  gemm_pre<0><<<gg, 256, 0, stream>>>(xh, xl, wkh, wkl, bk, khb, klb);

  conv_hilo<<<2048, 256, 0, stream>>>(value, xh, xl, N4);
  gemm_pre<2><<<gg, 256, 0, stream>>>(xh, xl, wvh, wvl, bv, vtb, nullptr);

  dim3 ga(S_LEN / 128, 2 * NHEAD);                 // (32, 16)
  attn_mfma<<<ga, 512, 0, stream>>>(qhb, qlb, khb, klb, vtb, bits, xh, xl);

  gemm_pre<1><<<gg, 256, 0, stream>>>(xh, xl, woh, wol, bo, out, nullptr);
}

// Round 5
// 348.474 us; speedup vs baseline: 9.3312x; 1.2602x over previous
//
#include <hip/hip_runtime.h>
#include <hip/hip_bf16.h>
#include <cstddef>
#include <cstdint>

// MultiHeadAttention: B=2, S=4096, D=512, H=8, HD=64
// Round 5: attention rebuilt on 32x32x16 swapped-operand MFMA (S^T = K*Q^T form),
// in-register softmax (lane owns a q-row), shfl-based P redistribution, wave-pair
// KV split + flash merge, 1 barrier/tile dbuf, setprio, defer-max.

#define S_LEN 4096
#define DMODEL 512
#define NHEAD 8
#define HDIM 64
#define NWORDS (S_LEN / 64)

typedef __bf16 bf16x8 __attribute__((ext_vector_type(8)));
typedef float f32x4 __attribute__((ext_vector_type(4)));
typedef float f32x16 __attribute__((ext_vector_type(16)));
typedef unsigned int u32x4 __attribute__((ext_vector_type(4)));
typedef unsigned short u16x4 __attribute__((ext_vector_type(4)));
typedef unsigned short u16x8 __attribute__((ext_vector_type(8)));

__device__ __forceinline__ unsigned short f2bf(float x) {
  return __builtin_bit_cast(unsigned short, (__bf16)x);
}
__device__ __forceinline__ float bf2f(unsigned short h) {
  union { unsigned u; float f; } v; v.u = ((unsigned)h) << 16; return v.f;
}
__device__ __forceinline__ unsigned pk2(float a, float b) {
  return (unsigned)f2bf(a) | ((unsigned)f2bf(b) << 16);
}
// swizzled ushort index into a [*][64] bf16 tile (128B rows, 16B chunk XOR row&7)
__device__ __forceinline__ int swzi(int row, int col) {
  return row * 64 + ((col & 7) | ((((col >> 3) ^ row) & 7) << 3));
}

// ---------------------------------------------------------------------------
__global__ __launch_bounds__(256) void pack_mask(
    const int* __restrict__ mask, unsigned long long* __restrict__ bits, int nwords)
{
  int gw = (blockIdx.x * blockDim.x + threadIdx.x) >> 6;
  int lane = threadIdx.x & 63;
  int nw = (gridDim.x * blockDim.x) >> 6;
  for (int w = gw; w < nwords; w += nw) {
    int v = mask[(size_t)w * 64 + lane];
    unsigned long long b = __ballot(v != 0);
    if (lane == 0) bits[w] = b;
  }
}

// ---------------------------------------------------------------------------
__global__ __launch_bounds__(256) void conv_hilo(
    const float* __restrict__ x, unsigned short* __restrict__ h,
    unsigned short* __restrict__ l, int n4)
{
  int i = blockIdx.x * 256 + threadIdx.x;
  int stride = gridDim.x * 256;
  for (; i < n4; i += stride) {
    float4 f = ((const float4*)x)[i];
    float ff[4] = {f.x, f.y, f.z, f.w};
    u16x4 hh, ll;
    #pragma unroll
    for (int j = 0; j < 4; ++j) {
      unsigned short hb = f2bf(ff[j]);
      hh[j] = hb;
      ll[j] = f2bf(ff[j] - bf2f(hb));
    }
    ((u16x4*)h)[i] = hh;
    ((u16x4*)l)[i] = ll;
  }
}

__global__ __launch_bounds__(256) void conv_w4(
    const float* __restrict__ w0, const float* __restrict__ w1,
    const float* __restrict__ w2, const float* __restrict__ w3,
    unsigned short* __restrict__ out)
{
  const float* src = (blockIdx.y == 0) ? w0 : (blockIdx.y == 1) ? w1 : (blockIdx.y == 2) ? w2 : w3;
  unsigned short* h = out + (size_t)blockIdx.y * 2 * 262144;
  unsigned short* l = h + 262144;
  int i = blockIdx.x * 256 + threadIdx.x;
  float4 f = ((const float4*)src)[i];
  float ff[4] = {f.x, f.y, f.z, f.w};
  u16x4 hh, ll;
  #pragma unroll
  for (int j = 0; j < 4; ++j) {
    unsigned short hb = f2bf(ff[j]);
    hh[j] = hb;
    ll[j] = f2bf(ff[j] - bf2f(hb));
  }
  ((u16x4*)h)[i] = hh;
  ((u16x4*)l)[i] = ll;
}

// ---------------------------------------------------------------------------
// GEMM from pre-converted bf16 hi/lo (unchanged from R4)
// ---------------------------------------------------------------------------
template <int MODE>
__global__ __launch_bounds__(256) void gemm_pre(
    const unsigned short* __restrict__ xh, const unsigned short* __restrict__ xl,
    const unsigned short* __restrict__ wh, const unsigned short* __restrict__ wl,
    const float* __restrict__ bias, void* __restrict__ out0, void* __restrict__ out1)
{
  __shared__ __align__(16) unsigned short SMEM[24576];
  unsigned short* Xh = SMEM;
  unsigned short* Xl = SMEM + 8192;
  unsigned short* Wh = SMEM + 16384;
  unsigned short* Wl = SMEM + 20480;

  const int t = threadIdx.x;
  const int lane = t & 63;
  const int w = t >> 6;
  const int c = lane & 15;
  const int g = lane >> 4;
  const int row0 = blockIdx.x * 128;
  const int col0 = blockIdx.y * 64;

  f32x4 acc[2][4];
  #pragma unroll
  for (int mi = 0; mi < 2; ++mi)
    #pragma unroll
    for (int n = 0; n < 4; ++n) acc[mi][n] = (f32x4){0.f, 0.f, 0.f, 0.f};

  u16x8 pxh[4], pxl[4], pwh[2], pwl[2];
  auto issue = [&](int k0) {
    #pragma unroll
    for (int i = 0; i < 4; ++i) {
      int id = i * 256 + t;
      int r = id >> 3, ch = id & 7;
      size_t off = (size_t)(row0 + r) * DMODEL + k0 + ch * 8;
      pxh[i] = *(const u16x8*)(xh + off);
      if (MODE != 2) pxl[i] = *(const u16x8*)(xl + off);
    }
    #pragma unroll
    for (int i = 0; i < 2; ++i) {
      int id = i * 256 + t;
      int r = id >> 3, ch = id & 7;
      size_t off = (size_t)(col0 + r) * DMODEL + k0 + ch * 8;
      pwh[i] = *(const u16x8*)(wh + off);
      if (MODE != 2) pwl[i] = *(const u16x8*)(wl + off);
    }
  };
  auto commit = [&]() {
    #pragma unroll
    for (int i = 0; i < 4; ++i) {
      int id = i * 256 + t;
      int r = id >> 3, ch = id & 7;
      int dst = r * 64 + (((ch ^ r) & 7) << 3);
      *(u16x8*)&Xh[dst] = pxh[i];
      if (MODE != 2) *(u16x8*)&Xl[dst] = pxl[i];
    }
    #pragma unroll
    for (int i = 0; i < 2; ++i) {
      int id = i * 256 + t;
      int r = id >> 3, ch = id & 7;
      int dst = r * 64 + (((ch ^ r) & 7) << 3);
      *(u16x8*)&Wh[dst] = pwh[i];
      if (MODE != 2) *(u16x8*)&Wl[dst] = pwl[i];
    }
  };

  issue(0);
  commit();
  __syncthreads();

  for (int k0 = 0; k0 < DMODEL; k0 += 64) {
    const bool more = (k0 + 64) < DMODEL;
    if (more) issue(k0 + 64);

    #pragma unroll
    for (int kk = 0; kk < 2; ++kk) {
      bf16x8 ah[2], al[2], bh_[4], bl_[4];
      #pragma unroll
      for (int mi = 0; mi < 2; ++mi) {
        int r = w * 32 + mi * 16 + c;
        ah[mi] = __builtin_bit_cast(bf16x8, *(const u16x8*)&Xh[swzi(r, (kk * 4 + g) * 8)]);
        if (MODE != 2) al[mi] = __builtin_bit_cast(bf16x8, *(const u16x8*)&Xl[swzi(r, (kk * 4 + g) * 8)]);
      }
      #pragma unroll
      for (int n = 0; n < 4; ++n) {
        int r = n * 16 + c;
        bh_[n] = __builtin_bit_cast(bf16x8, *(const u16x8*)&Wh[swzi(r, (kk * 4 + g) * 8)]);
        if (MODE != 2) bl_[n] = __builtin_bit_cast(bf16x8, *(const u16x8*)&Wl[swzi(r, (kk * 4 + g) * 8)]);
      }
      #pragma unroll
      for (int mi = 0; mi < 2; ++mi)
        #pragma unroll
        for (int n = 0; n < 4; ++n) {
          acc[mi][n] = __builtin_amdgcn_mfma_f32_16x16x32_bf16(ah[mi], bh_[n], acc[mi][n], 0, 0, 0);
          if (MODE != 2) {
            acc[mi][n] = __builtin_amdgcn_mfma_f32_16x16x32_bf16(al[mi], bh_[n], acc[mi][n], 0, 0, 0);
            acc[mi][n] = __builtin_amdgcn_mfma_f32_16x16x32_bf16(ah[mi], bl_[n], acc[mi][n], 0, 0, 0);
          }
        }
    }
    __syncthreads();
    if (more) {
      commit();
      __syncthreads();
    }
  }

  if (MODE == 0) {
    unsigned short* Yh = (unsigned short*)out0;
    unsigned short* Yl = (unsigned short*)out1;
    #pragma unroll
    for (int mi = 0; mi < 2; ++mi)
      #pragma unroll
      for (int n = 0; n < 4; ++n)
        #pragma unroll
        for (int j = 0; j < 4; ++j) {
          int rr = row0 + w * 32 + mi * 16 + g * 4 + j;
          int oo = col0 + n * 16 + c;
          float val = acc[mi][n][j] + bias[oo];
          int bb = rr >> 12, ss = rr & (S_LEN - 1), h2 = oo >> 6, hd = oo & 63;
          size_t idx = (((size_t)(bb * NHEAD + h2)) * S_LEN + ss) * HDIM + hd;
          unsigned short hb = f2bf(val);
          Yh[idx] = hb;
          Yl[idx] = f2bf(val - bf2f(hb));
        }
  } else if (MODE == 1) {
    float* Y = (float*)out0;
    #pragma unroll
    for (int mi = 0; mi < 2; ++mi)
      #pragma unroll
      for (int n = 0; n < 4; ++n)
        #pragma unroll
        for (int j = 0; j < 4; ++j) {
          int rr = row0 + w * 32 + mi * 16 + g * 4 + j;
          int oo = col0 + n * 16 + c;
          Y[(size_t)rr * DMODEL + oo] = acc[mi][n][j] + bias[oo];
        }
  } else {
    unsigned short* Ts = SMEM;   // [128][68]
    #pragma unroll
    for (int mi = 0; mi < 2; ++mi)
      #pragma unroll
      for (int n = 0; n < 4; ++n)
        #pragma unroll
        for (int j = 0; j < 4; ++j) {
          int r = w * 32 + mi * 16 + g * 4 + j;
          int o = n * 16 + c;
          Ts[r * 68 + o] = f2bf(acc[mi][n][j] + bias[col0 + o]);
        }
    __syncthreads();
    unsigned short* vt = (unsigned short*)out0;
    int bb = row0 >> 12, sbase = row0 & (S_LEN - 1), h2 = col0 >> 6;
    int d = t >> 2, s0 = (t & 3) * 32;
    size_t obase = ((size_t)((bb * NHEAD + h2) * HDIM + d)) * S_LEN + sbase + s0;
    #pragma unroll
    for (int i = 0; i < 4; ++i) {
      u16x8 v;
      #pragma unroll
      for (int jj = 0; jj < 8; ++jj) v[jj] = Ts[(s0 + i * 8 + jj) * 68 + d];
      *(u16x8*)(vt + obase + i * 8) = v;
    }
  }
}

// ---------------------------------------------------------------------------
// Flash attention on 32x32x16 MFMA, swapped operands.
// Block: 256 thr = 4 waves = 2 pairs; QBLK = 64 (pair p owns q-rows p*32+[0,32)).
// Within a pair, wave chunk=0 handles kv [0,32) of each tile, chunk=1 [32,64).
// Lane (c31,hi): owns q-row c31; holds S^T col q, rows kv=(r&3)+8*(r>>2)+4hi.
// ---------------------------------------------------------------------------
__global__ __launch_bounds__(256) void attn32(
    const unsigned short* __restrict__ qh, const unsigned short* __restrict__ ql,
    const unsigned short* __restrict__ kh, const unsigned short* __restrict__ kl,
    const unsigned short* __restrict__ vt, const unsigned long long* __restrict__ mbits,
    unsigned short* __restrict__ Oh, unsigned short* __restrict__ Ol)
{
  __shared__ __align__(16) unsigned short LDS[2][3][4096];   // [buf][Kh,Kl,Vt][64x64]

  const int t = threadIdx.x;
  const int lane = t & 63;
  const int w = t >> 6;
  const int pair = w >> 1;
  const int chunk = w & 1;
  const int c31 = lane & 31;
  const int hi = lane >> 5;

  // XCD-aware bijective swizzle of flattened grid (nwg=1024, 1024%8==0)
  const int nwg = gridDim.x;
  const int bid = blockIdx.x;
  const int lin = (bid & 7) * (nwg >> 3) + (bid >> 3);
  const int qi = lin & 63;
  const int bh = lin >> 6;
  const int q0 = qi * 64;
  const int b = bh >> 3, h = bh & 7;
  const int qrow = q0 + pair * 32 + c31;

  // Q fragments: B[row=d=16s+8hi+j][col=q]  ->  Q[qrow][16s+8hi+j]
  const unsigned short* Qhp = qh + ((size_t)bh * S_LEN + qrow) * HDIM;
  const unsigned short* Qlp = ql + ((size_t)bh * S_LEN + qrow) * HDIM;
  bf16x8 qhf[4], qlf[4];
  #pragma unroll
  for (int s = 0; s < 4; ++s) {
    qhf[s] = __builtin_bit_cast(bf16x8, *(const u16x8*)(Qhp + 16 * s + 8 * hi));
    qlf[s] = __builtin_bit_cast(bf16x8, *(const u16x8*)(Qlp + 16 * s + 8 * hi));
  }

  const unsigned short* Kbh = kh + (size_t)bh * S_LEN * HDIM;
  const unsigned short* Kbl = kl + (size_t)bh * S_LEN * HDIM;
  const unsigned short* Vbt = vt + (size_t)bh * HDIM * S_LEN;
  const unsigned long long* mptr = mbits + (size_t)(b * S_LEN + qrow) * NWORDS;

  // staging: 512 chunks per 64x64 array, 256 threads -> 2 each
  const int sr0 = t >> 3, sch = t & 7;
  const int sr1 = sr0 + 32;
  const int dst0 = sr0 * 64 + (((sch ^ sr0) & 7) << 3);
  const int dst1 = sr1 * 64 + (((sch ^ sr1) & 7) << 3);
  u16x8 pkh[2], pkl[2], pkv[2];
  auto issue = [&](int k0) {
    pkh[0] = *(const u16x8*)(Kbh + (size_t)(k0 + sr0) * HDIM + sch * 8);
    pkh[1] = *(const u16x8*)(Kbh + (size_t)(k0 + sr1) * HDIM + sch * 8);
    pkl[0] = *(const u16x8*)(Kbl + (size_t)(k0 + sr0) * HDIM + sch * 8);
    pkl[1] = *(const u16x8*)(Kbl + (size_t)(k0 + sr1) * HDIM + sch * 8);
    pkv[0] = *(const u16x8*)(Vbt + (size_t)sr0 * S_LEN + k0 + sch * 8);
    pkv[1] = *(const u16x8*)(Vbt + (size_t)sr1 * S_LEN + k0 + sch * 8);
  };
  auto commit = [&](int buf) {
    *(u16x8*)&LDS[buf][0][dst0] = pkh[0];
    *(u16x8*)&LDS[buf][0][dst1] = pkh[1];
    *(u16x8*)&LDS[buf][1][dst0] = pkl[0];
    *(u16x8*)&LDS[buf][1][dst1] = pkl[1];
    *(u16x8*)&LDS[buf][2][dst0] = pkv[0];
    *(u16x8*)&LDS[buf][2][dst1] = pkv[1];
  };

  f32x16 oacc0, oacc1;
  #pragma unroll
  for (int r = 0; r < 16; ++r) { oacc0[r] = 0.f; oacc1[r] = 0.f; }
  float mrow = -INFINITY, lrow = 0.f;

  unsigned long long m64 = mptr[0], m64n = 0;

  issue(0);
  commit(0);
  __syncthreads();

  int cur = 0;
  for (int kt = 0; kt < S_LEN / 64; ++kt) {
    const bool more = kt < (S_LEN / 64 - 1);
    if (more) {
      issue((kt + 1) * 64);
      m64n = mptr[kt + 1];
    }
    const unsigned short* Kh_ = &LDS[cur][0][0];
    const unsigned short* Kl_ = &LDS[cur][1][0];
    const unsigned short* Vt_ = &LDS[cur][2][0];

    // ---- scores: S^T chunk = mfma(A=K rows, B=Q), 3-pass hi/lo ----
    f32x16 p;
    #pragma unroll
    for (int r = 0; r < 16; ++r) p[r] = 0.f;
    __builtin_amdgcn_s_setprio(1);
    #pragma unroll
    for (int s = 0; s < 4; ++s) {
      int idx = swzi(chunk * 32 + c31, 16 * s + 8 * hi);
      bf16x8 ah = __builtin_bit_cast(bf16x8, *(const u16x8*)&Kh_[idx]);
      bf16x8 al = __builtin_bit_cast(bf16x8, *(const u16x8*)&Kl_[idx]);
      p = __builtin_amdgcn_mfma_f32_32x32x16_bf16(ah, qhf[s], p, 0, 0, 0);
      p = __builtin_amdgcn_mfma_f32_32x32x16_bf16(al, qhf[s], p, 0, 0, 0);
      p = __builtin_amdgcn_mfma_f32_32x32x16_bf16(ah, qlf[s], p, 0, 0, 0);
    }
    __builtin_amdgcn_s_setprio(0);

    // ---- mask (lane-local bits) ----
    unsigned half = chunk ? (unsigned)(m64 >> 32) : (unsigned)m64;
    unsigned hs = half >> (hi * 4);
    #pragma unroll
    for (int r = 0; r < 16; ++r) {
      int bs = (r & 3) + 8 * (r >> 2);
      p[r] = ((hs >> bs) & 1u) ? p[r] : -1.0e9f;
    }

    // ---- in-register online softmax for row q=c31 (32 kv of this chunk) ----
    float a0 = fmaxf(p[0], p[1]),  a1 = fmaxf(p[2], p[3]);
    float a2 = fmaxf(p[4], p[5]),  a3 = fmaxf(p[6], p[7]);
    float a4 = fmaxf(p[8], p[9]),  a5 = fmaxf(p[10], p[11]);
    float a6 = fmaxf(p[12], p[13]), a7 = fmaxf(p[14], p[15]);
    float mx = fmaxf(fmaxf(fmaxf(a0, a1), fmaxf(a2, a3)),
                     fmaxf(fmaxf(a4, a5), fmaxf(a6, a7)));
    mx = fmaxf(mx, __shfl_xor(mx, 32, 64));

    float mn, scl;
    if (__all(mx <= mrow + 8.0f)) {      // defer-max: skip rescale
      mn = mrow;
      scl = 1.0f;
    } else {
      mn = fmaxf(mrow, mx);
      scl = __expf(mrow - mn);
      mrow = mn;
      oacc0 *= scl;
      oacc1 *= scl;
    }
    #pragma unroll
    for (int r = 0; r < 16; ++r) p[r] = __expf(p[r] - mn);
    float s0_ = (p[0] + p[1]) + (p[2] + p[3]);
    float s1_ = (p[4] + p[5]) + (p[6] + p[7]);
    float s2_ = (p[8] + p[9]) + (p[10] + p[11]);
    float s3_ = (p[12] + p[13]) + (p[14] + p[15]);
    float ps = (s0_ + s1_) + (s2_ + s3_);
    ps += __shfl_xor(ps, 32, 64);
    lrow = lrow * scl + ps;

    // ---- P redistribution: build B-frags P^T[k][q] for 2 K=16 slots ----
    // word W[rq][bq] packs p[4rq+2bq], p[4rq+2bq+1]  (k = 8rq+4hi+2bq+{0,1})
    unsigned W[4][2];
    #pragma unroll
    for (int rq = 0; rq < 4; ++rq) {
      W[rq][0] = pk2(p[4 * rq + 0], p[4 * rq + 1]);
      W[rq][1] = pk2(p[4 * rq + 2], p[4 * rq + 3]);
    }
    bf16x8 pf[2];
    #pragma unroll
    for (int s2 = 0; s2 < 2; ++s2) {
      unsigned keep0 = hi ? W[2 * s2 + 1][0] : W[2 * s2][0];
      unsigned keep1 = hi ? W[2 * s2 + 1][1] : W[2 * s2][1];
      unsigned send0 = hi ? W[2 * s2][0] : W[2 * s2 + 1][0];
      unsigned send1 = hi ? W[2 * s2][1] : W[2 * s2 + 1][1];
      unsigned recv0 = (unsigned)__shfl_xor((int)send0, 32, 64);
      unsigned recv1 = (unsigned)__shfl_xor((int)send1, 32, 64);
      u32x4 fw;
      fw[0] = hi ? recv0 : keep0;
      fw[1] = hi ? recv1 : keep1;
      fw[2] = hi ? keep0 : recv0;
      fw[3] = hi ? keep1 : recv1;
      pf[s2] = __builtin_bit_cast(bf16x8, fw);
    }

    // ---- PV: O^T chunk = mfma(A=V^T rows d, B=P^T) ----
    __builtin_amdgcn_s_setprio(1);
    #pragma unroll
    for (int s2 = 0; s2 < 2; ++s2) {
      int col = chunk * 32 + 16 * s2 + 8 * hi;
      bf16x8 vf0 = __builtin_bit_cast(bf16x8, *(const u16x8*)&Vt_[swzi(c31, col)]);
      bf16x8 vf1 = __builtin_bit_cast(bf16x8, *(const u16x8*)&Vt_[swzi(32 + c31, col)]);
      oacc0 = __builtin_amdgcn_mfma_f32_32x32x16_bf16(vf0, pf[s2], oacc0, 0, 0, 0);
      oacc1 = __builtin_amdgcn_mfma_f32_32x32x16_bf16(vf1, pf[s2], oacc1, 0, 0, 0);
    }
    __builtin_amdgcn_s_setprio(0);

    if (more) {
      m64 = m64n;
      commit(cur ^ 1);
    }
    __syncthreads();
    cur ^= 1;
  }

  // ---- flash merge across the wave pair (chunk 0 + chunk 1), via LDS ----
  float* mb = (float*)&LDS[0][0][0];   // [2 pair][2 hi][32 c31][36]
  const int mi = ((pair * 2 + hi) * 32 + c31) * 36;
  if (chunk == 1) {
    #pragma unroll
    for (int q4 = 0; q4 < 4; ++q4) {
      *(f32x4*)&mb[mi + q4 * 4]      = (f32x4){oacc0[q4 * 4], oacc0[q4 * 4 + 1], oacc0[q4 * 4 + 2], oacc0[q4 * 4 + 3]};
      *(f32x4*)&mb[mi + 16 + q4 * 4] = (f32x4){oacc1[q4 * 4], oacc1[q4 * 4 + 1], oacc1[q4 * 4 + 2], oacc1[q4 * 4 + 3]};
    }
    mb[mi + 32] = mrow;
    mb[mi + 33] = lrow;
  }
  __syncthreads();
  if (chunk == 0) {
    float m1 = mb[mi + 32], l1 = mb[mi + 33];
    float mS = fmaxf(mrow, m1);
    float f0 = __expf(mrow - mS), f1 = __expf(m1 - mS);
    float lS = lrow * f0 + l1 * f1;
    float inv = 1.0f / lS;
    size_t obase = ((size_t)b * S_LEN + qrow) * DMODEL + h * HDIM;
    #pragma unroll
    for (int c2 = 0; c2 < 2; ++c2) {
      #pragma unroll
      for (int rq = 0; rq < 4; ++rq) {
        u16x4 hv, lv;
        #pragma unroll
        for (int rb = 0; rb < 4; ++rb) {
          int reg = 4 * rq + rb;
          float o0 = (c2 == 0) ? oacc0[reg] : oacc1[reg];
          float o1 = mb[mi + c2 * 16 + reg];
          float val = (o0 * f0 + o1 * f1) * inv;
          unsigned short hb = f2bf(val);
          hv[rb] = hb;
          lv[rb] = f2bf(val - bf2f(hb));
        }
        int dbase = 32 * c2 + 8 * rq + 4 * hi;
        *(u16x4*)(Oh + obase + dbase) = hv;
        *(u16x4*)(Ol + obase + dbase) = lv;
      }
    }
  }
}

// ---------------------------------------------------------------------------
extern "C" void kernel_launch(void* const* d_in, const int* in_sizes, int n_in,
                              void* d_out, int out_size, void* d_ws, size_t ws_size,
                              hipStream_t stream) {
  const float* query = (const float*)d_in[0];
  const float* key   = (const float*)d_in[1];
  const float* value = (const float*)d_in[2];
  const int*   mask  = (const int*)  d_in[3];
  const float* Wq = (const float*)d_in[4];
  const float* bq = (const float*)d_in[5];
  const float* Wk = (const float*)d_in[6];
  const float* bk = (const float*)d_in[7];
  const float* Wv = (const float*)d_in[8];
  const float* bv = (const float*)d_in[9];
  const float* Wo = (const float*)d_in[10];
  const float* bo = (const float*)d_in[11];
  float* out = (float*)d_out;

  const size_t PER = (size_t)2 * S_LEN * DMODEL;   // 4,194,304 elements
  const size_t WSZ = (size_t)DMODEL * DMODEL;      // 262,144

  unsigned short* p = (unsigned short*)d_ws;
  unsigned short* wbuf = p;                        // 4 MB
  unsigned short* xh = p + 8 * WSZ;
  unsigned short* xl = xh + PER;
  unsigned short* qhb = xl + PER;
  unsigned short* qlb = qhb + PER;
  unsigned short* khb = qlb + PER;
  unsigned short* klb = khb + PER;
  unsigned short* vtb = klb + PER;                 // total 60 MB

  unsigned short* wqh = wbuf + 0 * 2 * WSZ, *wql = wqh + WSZ;
  unsigned short* wkh = wbuf + 1 * 2 * WSZ, *wkl = wkh + WSZ;
  unsigned short* wvh = wbuf + 2 * 2 * WSZ, *wvl = wvh + WSZ;
  unsigned short* woh = wbuf + 3 * 2 * WSZ, *wol = woh + WSZ;

  unsigned long long* bits = (unsigned long long*)d_out;   // overwritten by final GEMM
  pack_mask<<<2048, 256, 0, stream>>>(mask, bits, 2 * S_LEN * NWORDS);
  conv_w4<<<dim3(256, 4), 256, 0, stream>>>(Wq, Wk, Wv, Wo, wbuf);

  dim3 gg(2 * S_LEN / 128, DMODEL / 64);           // (64, 8)
  const int N4 = (int)(PER / 4);

  conv_hilo<<<2048, 256, 0, stream>>>(query, xh, xl, N4);
  gemm_pre<0><<<gg, 256, 0, stream>>>(xh, xl, wqh, wql, bq, qhb, qlb);

  conv_hilo<<<2048, 256, 0, stream>>>(key, xh, xl, N4);
  gemm_pre<0><<<gg, 256, 0, stream>>>(xh, xl, wkh, wkl, bk, khb, klb);

  conv_hilo<<<2048, 256, 0, stream>>>(value, xh, xl, N4);
  gemm_pre<2><<<gg, 256, 0, stream>>>(xh, xl, wvh, wvl, bv, vtb, nullptr);

  attn32<<<1024, 256, 0, stream>>>(qhb, qlb, khb, klb, vtb, bits, xh, xl);

  gemm_pre<1><<<gg, 256, 0, stream>>>(xh, xl, woh, wol, bo, out, nullptr);
}

// Round 6
// 274.703 us; speedup vs baseline: 11.8371x; 1.2686x over previous
//
#include <hip/hip_runtime.h>
#include <hip/hip_bf16.h>
#include <cstddef>
#include <cstdint>

// MultiHeadAttention: B=2, S=4096, D=512, H=8, HD=64
// Round 6: attention on single-pass fp16 MFMA (Q pre-scaled by log2e -> exp2
// softmax), K/V single fp16 in LDS (32KB -> 5 blocks/CU), max3 trees, pkrtz
// P-packing. Projections remain 3-pass bf16 hi/lo internally.

#define S_LEN 4096
#define DMODEL 512
#define NHEAD 8
#define HDIM 64
#define NWORDS (S_LEN / 64)

typedef __bf16 bf16x8 __attribute__((ext_vector_type(8)));
typedef _Float16 f16x8 __attribute__((ext_vector_type(8)));
typedef _Float16 f16x2 __attribute__((ext_vector_type(2)));
typedef float f32x4 __attribute__((ext_vector_type(4)));
typedef float f32x16 __attribute__((ext_vector_type(16)));
typedef unsigned int u32x4 __attribute__((ext_vector_type(4)));
typedef unsigned short u16x4 __attribute__((ext_vector_type(4)));
typedef unsigned short u16x8 __attribute__((ext_vector_type(8)));

__device__ __forceinline__ unsigned short f2bf(float x) {
  return __builtin_bit_cast(unsigned short, (__bf16)x);
}
__device__ __forceinline__ float bf2f(unsigned short h) {
  union { unsigned u; float f; } v; v.u = ((unsigned)h) << 16; return v.f;
}
__device__ __forceinline__ float fast_exp2(float x) {
#if __has_builtin(__builtin_amdgcn_exp2f)
  return __builtin_amdgcn_exp2f(x);
#else
  return __expf(x * 0.69314718056f);
#endif
}
__device__ __forceinline__ float max3f(float a, float b, float c) {
  return fmaxf(fmaxf(a, b), c);
}
// swizzled ushort index into a [*][64] 16-bit tile (128B rows, 16B chunk XOR row&7)
__device__ __forceinline__ int swzi(int row, int col) {
  return row * 64 + ((col & 7) | ((((col >> 3) ^ row) & 7) << 3));
}

// ---------------------------------------------------------------------------
__global__ __launch_bounds__(256) void pack_mask(
    const int* __restrict__ mask, unsigned long long* __restrict__ bits, int nwords)
{
  int gw = (blockIdx.x * blockDim.x + threadIdx.x) >> 6;
  int lane = threadIdx.x & 63;
  int nw = (gridDim.x * blockDim.x) >> 6;
  for (int w = gw; w < nwords; w += nw) {
    int v = mask[(size_t)w * 64 + lane];
    unsigned long long b = __ballot(v != 0);
    if (lane == 0) bits[w] = b;
  }
}

// ---------------------------------------------------------------------------
__global__ __launch_bounds__(256) void conv_hilo(
    const float* __restrict__ x, unsigned short* __restrict__ h,
    unsigned short* __restrict__ l, int n4)
{
  int i = blockIdx.x * 256 + threadIdx.x;
  int stride = gridDim.x * 256;
  for (; i < n4; i += stride) {
    float4 f = ((const float4*)x)[i];
    float ff[4] = {f.x, f.y, f.z, f.w};
    u16x4 hh, ll;
    #pragma unroll
    for (int j = 0; j < 4; ++j) {
      unsigned short hb = f2bf(ff[j]);
      hh[j] = hb;
      ll[j] = f2bf(ff[j] - bf2f(hb));
    }
    ((u16x4*)h)[i] = hh;
    ((u16x4*)l)[i] = ll;
  }
}

__global__ __launch_bounds__(256) void conv_w4(
    const float* __restrict__ w0, const float* __restrict__ w1,
    const float* __restrict__ w2, const float* __restrict__ w3,
    unsigned short* __restrict__ out)
{
  const float* src = (blockIdx.y == 0) ? w0 : (blockIdx.y == 1) ? w1 : (blockIdx.y == 2) ? w2 : w3;
  unsigned short* h = out + (size_t)blockIdx.y * 2 * 262144;
  unsigned short* l = h + 262144;
  int i = blockIdx.x * 256 + threadIdx.x;
  float4 f = ((const float4*)src)[i];
  float ff[4] = {f.x, f.y, f.z, f.w};
  u16x4 hh, ll;
  #pragma unroll
  for (int j = 0; j < 4; ++j) {
    unsigned short hb = f2bf(ff[j]);
    hh[j] = hb;
    ll[j] = f2bf(ff[j] - bf2f(hb));
  }
  ((u16x4*)h)[i] = hh;
  ((u16x4*)l)[i] = ll;
}

// ---------------------------------------------------------------------------
// GEMM from pre-converted bf16 hi/lo (3-pass bf16 MFMA internally).
// MODE 0: out single fp16 head-split [B,H,S,HD], value scaled by oscale (Q,K)
// MODE 1: out f32 flat [N,DMODEL]                                   (final)
// MODE 2: out single fp16 transposed [B,H,HD,S]                     (V)
// ---------------------------------------------------------------------------
template <int MODE>
__global__ __launch_bounds__(256) void gemm_pre(
    const unsigned short* __restrict__ xh, const unsigned short* __restrict__ xl,
    const unsigned short* __restrict__ wh, const unsigned short* __restrict__ wl,
    const float* __restrict__ bias, void* __restrict__ out0, void* __restrict__ out1,
    float oscale)
{
  __shared__ __align__(16) unsigned short SMEM[24576];
  unsigned short* Xh = SMEM;
  unsigned short* Xl = SMEM + 8192;
  unsigned short* Wh = SMEM + 16384;
  unsigned short* Wl = SMEM + 20480;

  const int t = threadIdx.x;
  const int lane = t & 63;
  const int w = t >> 6;
  const int c = lane & 15;
  const int g = lane >> 4;
  const int row0 = blockIdx.x * 128;
  const int col0 = blockIdx.y * 64;

  f32x4 acc[2][4];
  #pragma unroll
  for (int mi = 0; mi < 2; ++mi)
    #pragma unroll
    for (int n = 0; n < 4; ++n) acc[mi][n] = (f32x4){0.f, 0.f, 0.f, 0.f};

  u16x8 pxh[4], pxl[4], pwh[2], pwl[2];
  auto issue = [&](int k0) {
    #pragma unroll
    for (int i = 0; i < 4; ++i) {
      int id = i * 256 + t;
      int r = id >> 3, ch = id & 7;
      size_t off = (size_t)(row0 + r) * DMODEL + k0 + ch * 8;
      pxh[i] = *(const u16x8*)(xh + off);
      pxl[i] = *(const u16x8*)(xl + off);
    }
    #pragma unroll
    for (int i = 0; i < 2; ++i) {
      int id = i * 256 + t;
      int r = id >> 3, ch = id & 7;
      size_t off = (size_t)(col0 + r) * DMODEL + k0 + ch * 8;
      pwh[i] = *(const u16x8*)(wh + off);
      pwl[i] = *(const u16x8*)(wl + off);
    }
  };
  auto commit = [&]() {
    #pragma unroll
    for (int i = 0; i < 4; ++i) {
      int id = i * 256 + t;
      int r = id >> 3, ch = id & 7;
      int dst = r * 64 + (((ch ^ r) & 7) << 3);
      *(u16x8*)&Xh[dst] = pxh[i];
      *(u16x8*)&Xl[dst] = pxl[i];
    }
    #pragma unroll
    for (int i = 0; i < 2; ++i) {
      int id = i * 256 + t;
      int r = id >> 3, ch = id & 7;
      int dst = r * 64 + (((ch ^ r) & 7) << 3);
      *(u16x8*)&Wh[dst] = pwh[i];
      *(u16x8*)&Wl[dst] = pwl[i];
    }
  };

  issue(0);
  commit();
  __syncthreads();

  for (int k0 = 0; k0 < DMODEL; k0 += 64) {
    const bool more = (k0 + 64) < DMODEL;
    if (more) issue(k0 + 64);

    #pragma unroll
    for (int kk = 0; kk < 2; ++kk) {
      bf16x8 ah[2], al[2], bh_[4], bl_[4];
      #pragma unroll
      for (int mi = 0; mi < 2; ++mi) {
        int r = w * 32 + mi * 16 + c;
        ah[mi] = __builtin_bit_cast(bf16x8, *(const u16x8*)&Xh[swzi(r, (kk * 4 + g) * 8)]);
        al[mi] = __builtin_bit_cast(bf16x8, *(const u16x8*)&Xl[swzi(r, (kk * 4 + g) * 8)]);
      }
      #pragma unroll
      for (int n = 0; n < 4; ++n) {
        int r = n * 16 + c;
        bh_[n] = __builtin_bit_cast(bf16x8, *(const u16x8*)&Wh[swzi(r, (kk * 4 + g) * 8)]);
        bl_[n] = __builtin_bit_cast(bf16x8, *(const u16x8*)&Wl[swzi(r, (kk * 4 + g) * 8)]);
      }
      #pragma unroll
      for (int mi = 0; mi < 2; ++mi)
        #pragma unroll
        for (int n = 0; n < 4; ++n) {
          acc[mi][n] = __builtin_amdgcn_mfma_f32_16x16x32_bf16(ah[mi], bh_[n], acc[mi][n], 0, 0, 0);
          acc[mi][n] = __builtin_amdgcn_mfma_f32_16x16x32_bf16(al[mi], bh_[n], acc[mi][n], 0, 0, 0);
          acc[mi][n] = __builtin_amdgcn_mfma_f32_16x16x32_bf16(ah[mi], bl_[n], acc[mi][n], 0, 0, 0);
        }
    }
    __syncthreads();
    if (more) {
      commit();
      __syncthreads();
    }
  }

  if (MODE == 0) {
    unsigned short* Yf = (unsigned short*)out0;
    #pragma unroll
    for (int mi = 0; mi < 2; ++mi)
      #pragma unroll
      for (int n = 0; n < 4; ++n)
        #pragma unroll
        for (int j = 0; j < 4; ++j) {
          int rr = row0 + w * 32 + mi * 16 + g * 4 + j;
          int oo = col0 + n * 16 + c;
          float val = (acc[mi][n][j] + bias[oo]) * oscale;
          int bb = rr >> 12, ss = rr & (S_LEN - 1), h2 = oo >> 6, hd = oo & 63;
          size_t idx = (((size_t)(bb * NHEAD + h2)) * S_LEN + ss) * HDIM + hd;
          Yf[idx] = __builtin_bit_cast(unsigned short, (_Float16)val);
        }
  } else if (MODE == 1) {
    float* Y = (float*)out0;
    #pragma unroll
    for (int mi = 0; mi < 2; ++mi)
      #pragma unroll
      for (int n = 0; n < 4; ++n)
        #pragma unroll
        for (int j = 0; j < 4; ++j) {
          int rr = row0 + w * 32 + mi * 16 + g * 4 + j;
          int oo = col0 + n * 16 + c;
          Y[(size_t)rr * DMODEL + oo] = acc[mi][n][j] + bias[oo];
        }
  } else {
    unsigned short* Ts = SMEM;   // [128][68] fp16
    #pragma unroll
    for (int mi = 0; mi < 2; ++mi)
      #pragma unroll
      for (int n = 0; n < 4; ++n)
        #pragma unroll
        for (int j = 0; j < 4; ++j) {
          int r = w * 32 + mi * 16 + g * 4 + j;
          int o = n * 16 + c;
          Ts[r * 68 + o] = __builtin_bit_cast(unsigned short, (_Float16)(acc[mi][n][j] + bias[col0 + o]));
        }
    __syncthreads();
    unsigned short* vt = (unsigned short*)out0;
    int bb = row0 >> 12, sbase = row0 & (S_LEN - 1), h2 = col0 >> 6;
    int d = t >> 2, s0 = (t & 3) * 32;
    size_t obase = ((size_t)((bb * NHEAD + h2) * HDIM + d)) * S_LEN + sbase + s0;
    #pragma unroll
    for (int i = 0; i < 4; ++i) {
      u16x8 v;
      #pragma unroll
      for (int jj = 0; jj < 8; ++jj) v[jj] = Ts[(s0 + i * 8 + jj) * 68 + d];
      *(u16x8*)(vt + obase + i * 8) = v;
    }
  }
}

// ---------------------------------------------------------------------------
// Flash attention on 32x32x16 fp16 MFMA, swapped operands, exp2 domain.
// Block: 256 thr = 4 waves = 2 pairs; QBLK=64; wave chunk halves each KV tile.
// ---------------------------------------------------------------------------
__global__ __launch_bounds__(256) void attn32(
    const unsigned short* __restrict__ qf, const unsigned short* __restrict__ kf,
    const unsigned short* __restrict__ vt, const unsigned long long* __restrict__ mbits,
    unsigned short* __restrict__ Oh, unsigned short* __restrict__ Ol)
{
  __shared__ __align__(16) unsigned short LDS[2][2][4096];   // [buf][K,Vt][64x64] fp16 = 32KB

  const int t = threadIdx.x;
  const int lane = t & 63;
  const int w = t >> 6;
  const int pair = w >> 1;
  const int chunk = w & 1;
  const int c31 = lane & 31;
  const int hi = lane >> 5;

  // XCD-aware bijective swizzle (nwg=1024, 1024%8==0)
  const int nwg = gridDim.x;
  const int bid = blockIdx.x;
  const int lin = (bid & 7) * (nwg >> 3) + (bid >> 3);
  const int qi = lin & 63;
  const int bh = lin >> 6;
  const int q0 = qi * 64;
  const int b = bh >> 3, h = bh & 7;
  const int qrow = q0 + pair * 32 + c31;

  // Q fragments (fp16, already scaled by log2e)
  const unsigned short* Qp = qf + ((size_t)bh * S_LEN + qrow) * HDIM;
  f16x8 qfr[4];
  #pragma unroll
  for (int s = 0; s < 4; ++s)
    qfr[s] = __builtin_bit_cast(f16x8, *(const u16x8*)(Qp + 16 * s + 8 * hi));

  const unsigned short* Kb = kf + (size_t)bh * S_LEN * HDIM;
  const unsigned short* Vbt = vt + (size_t)bh * HDIM * S_LEN;
  const unsigned long long* mptr = mbits + (size_t)(b * S_LEN + qrow) * NWORDS;

  // staging: 512 chunks per 64x64 array, 256 threads -> 2 each
  const int sr0 = t >> 3, sch = t & 7;
  const int sr1 = sr0 + 32;
  const int dst0 = sr0 * 64 + (((sch ^ sr0) & 7) << 3);
  const int dst1 = sr1 * 64 + (((sch ^ sr1) & 7) << 3);
  u16x8 pkk[2], pkv[2];
  auto issue = [&](int k0) {
    pkk[0] = *(const u16x8*)(Kb + (size_t)(k0 + sr0) * HDIM + sch * 8);
    pkk[1] = *(const u16x8*)(Kb + (size_t)(k0 + sr1) * HDIM + sch * 8);
    pkv[0] = *(const u16x8*)(Vbt + (size_t)sr0 * S_LEN + k0 + sch * 8);
    pkv[1] = *(const u16x8*)(Vbt + (size_t)sr1 * S_LEN + k0 + sch * 8);
  };
  auto commit = [&](int buf) {
    *(u16x8*)&LDS[buf][0][dst0] = pkk[0];
    *(u16x8*)&LDS[buf][0][dst1] = pkk[1];
    *(u16x8*)&LDS[buf][1][dst0] = pkv[0];
    *(u16x8*)&LDS[buf][1][dst1] = pkv[1];
  };

  f32x16 oacc0, oacc1;
  #pragma unroll
  for (int r = 0; r < 16; ++r) { oacc0[r] = 0.f; oacc1[r] = 0.f; }
  float mrow = -INFINITY, lrow = 0.f;

  unsigned long long m64 = mptr[0], m64n = 0;

  issue(0);
  commit(0);
  __syncthreads();

  int cur = 0;
  for (int kt = 0; kt < S_LEN / 64; ++kt) {
    const bool more = kt < (S_LEN / 64 - 1);
    if (more) {
      issue((kt + 1) * 64);
      m64n = mptr[kt + 1];
    }
    const unsigned short* K_ = &LDS[cur][0][0];
    const unsigned short* Vt_ = &LDS[cur][1][0];

    // ---- scores: S^T chunk = mfma(A=K rows, B=Q), single-pass fp16 ----
    f32x16 p;
    #pragma unroll
    for (int r = 0; r < 16; ++r) p[r] = 0.f;
    __builtin_amdgcn_s_setprio(1);
    #pragma unroll
    for (int s = 0; s < 4; ++s) {
      int idx = swzi(chunk * 32 + c31, 16 * s + 8 * hi);
      f16x8 kfr = __builtin_bit_cast(f16x8, *(const u16x8*)&K_[idx]);
      p = __builtin_amdgcn_mfma_f32_32x32x16_f16(kfr, qfr[s], p, 0, 0, 0);
    }
    __builtin_amdgcn_s_setprio(0);

    // ---- mask (lane-local bits) ----
    unsigned half = chunk ? (unsigned)(m64 >> 32) : (unsigned)m64;
    unsigned hs = half >> (hi * 4);
    #pragma unroll
    for (int r = 0; r < 16; ++r) {
      int bs = (r & 3) + 8 * (r >> 2);
      p[r] = ((hs >> bs) & 1u) ? p[r] : -1.0e9f;
    }

    // ---- in-register online softmax (log2 domain) ----
    float t0 = max3f(p[0], p[1], p[2]);
    float t1 = max3f(p[3], p[4], p[5]);
    float t2 = max3f(p[6], p[7], p[8]);
    float t3 = max3f(p[9], p[10], p[11]);
    float t4 = max3f(p[12], p[13], p[14]);
    float mx = fmaxf(max3f(t0, t1, t2), max3f(t3, t4, p[15]));
    mx = fmaxf(mx, __shfl_xor(mx, 32, 64));

    float mn, scl;
    if (__all(mx <= mrow + 11.54f)) {    // defer-max (e^8 in log2 units)
      mn = mrow;
      scl = 1.0f;
    } else {
      mn = fmaxf(mrow, mx);
      scl = fast_exp2(mrow - mn);
      mrow = mn;
      oacc0 *= scl;
      oacc1 *= scl;
    }
    #pragma unroll
    for (int r = 0; r < 16; ++r) p[r] = fast_exp2(p[r] - mn);
    float s0_ = (p[0] + p[1]) + (p[2] + p[3]);
    float s1_ = (p[4] + p[5]) + (p[6] + p[7]);
    float s2_ = (p[8] + p[9]) + (p[10] + p[11]);
    float s3_ = (p[12] + p[13]) + (p[14] + p[15]);
    float ps = (s0_ + s1_) + (s2_ + s3_);
    ps += __shfl_xor(ps, 32, 64);
    lrow = lrow * scl + ps;

    // ---- P redistribution: fp16 pairs, build B-frags for 2 K=16 slots ----
    unsigned W[4][2];
    #pragma unroll
    for (int rq = 0; rq < 4; ++rq) {
      W[rq][0] = __builtin_bit_cast(unsigned, __builtin_amdgcn_cvt_pkrtz(p[4 * rq + 0], p[4 * rq + 1]));
      W[rq][1] = __builtin_bit_cast(unsigned, __builtin_amdgcn_cvt_pkrtz(p[4 * rq + 2], p[4 * rq + 3]));
    }
    f16x8 pf[2];
    #pragma unroll
    for (int s2 = 0; s2 < 2; ++s2) {
      unsigned keep0 = hi ? W[2 * s2 + 1][0] : W[2 * s2][0];
      unsigned keep1 = hi ? W[2 * s2 + 1][1] : W[2 * s2][1];
      unsigned send0 = hi ? W[2 * s2][0] : W[2 * s2 + 1][0];
      unsigned send1 = hi ? W[2 * s2][1] : W[2 * s2 + 1][1];
      unsigned recv0 = (unsigned)__shfl_xor((int)send0, 32, 64);
      unsigned recv1 = (unsigned)__shfl_xor((int)send1, 32, 64);
      u32x4 fw;
      fw[0] = hi ? recv0 : keep0;
      fw[1] = hi ? recv1 : keep1;
      fw[2] = hi ? keep0 : recv0;
      fw[3] = hi ? keep1 : recv1;
      pf[s2] = __builtin_bit_cast(f16x8, fw);
    }

    // ---- PV: O^T chunk = mfma(A=V^T rows d, B=P^T) ----
    __builtin_amdgcn_s_setprio(1);
    #pragma unroll
    for (int s2 = 0; s2 < 2; ++s2) {
      int col = chunk * 32 + 16 * s2 + 8 * hi;
      f16x8 vf0 = __builtin_bit_cast(f16x8, *(const u16x8*)&Vt_[swzi(c31, col)]);
      f16x8 vf1 = __builtin_bit_cast(f16x8, *(const u16x8*)&Vt_[swzi(32 + c31, col)]);
      oacc0 = __builtin_amdgcn_mfma_f32_32x32x16_f16(vf0, pf[s2], oacc0, 0, 0, 0);
      oacc1 = __builtin_amdgcn_mfma_f32_32x32x16_f16(vf1, pf[s2], oacc1, 0, 0, 0);
    }
    __builtin_amdgcn_s_setprio(0);

    if (more) {
      m64 = m64n;
      commit(cur ^ 1);
    }
    __syncthreads();
    cur ^= 1;
  }

  // ---- flash merge across the wave pair, via LDS ----
  float* mb = (float*)&LDS[0][0][0];   // [2 pair][2 hi][32 c31][36]
  const int mi = ((pair * 2 + hi) * 32 + c31) * 36;
  if (chunk == 1) {
    #pragma unroll
    for (int q4 = 0; q4 < 4; ++q4) {
      *(f32x4*)&mb[mi + q4 * 4]      = (f32x4){oacc0[q4 * 4], oacc0[q4 * 4 + 1], oacc0[q4 * 4 + 2], oacc0[q4 * 4 + 3]};
      *(f32x4*)&mb[mi + 16 + q4 * 4] = (f32x4){oacc1[q4 * 4], oacc1[q4 * 4 + 1], oacc1[q4 * 4 + 2], oacc1[q4 * 4 + 3]};
    }
    mb[mi + 32] = mrow;
    mb[mi + 33] = lrow;
  }
  __syncthreads();
  if (chunk == 0) {
    float m1 = mb[mi + 32], l1 = mb[mi + 33];
    float mS = fmaxf(mrow, m1);
    float f0 = fast_exp2(mrow - mS), f1 = fast_exp2(m1 - mS);
    float lS = lrow * f0 + l1 * f1;
    float inv = 1.0f / lS;
    size_t obase = ((size_t)b * S_LEN + qrow) * DMODEL + h * HDIM;
    #pragma unroll
    for (int c2 = 0; c2 < 2; ++c2) {
      #pragma unroll
      for (int rq = 0; rq < 4; ++rq) {
        u16x4 hv, lv;
        #pragma unroll
        for (int rb = 0; rb < 4; ++rb) {
          int reg = 4 * rq + rb;
          float o0 = (c2 == 0) ? oacc0[reg] : oacc1[reg];
          float o1 = mb[mi + c2 * 16 + reg];
          float val = (o0 * f0 + o1 * f1) * inv;
          unsigned short hb = f2bf(val);
          hv[rb] = hb;
          lv[rb] = f2bf(val - bf2f(hb));
        }
        int dbase = 32 * c2 + 8 * rq + 4 * hi;
        *(u16x4*)(Oh + obase + dbase) = hv;
        *(u16x4*)(Ol + obase + dbase) = lv;
      }
    }
  }
}

// ---------------------------------------------------------------------------
extern "C" void kernel_launch(void* const* d_in, const int* in_sizes, int n_in,
                              void* d_out, int out_size, void* d_ws, size_t ws_size,
                              hipStream_t stream) {
  const float* query = (const float*)d_in[0];
  const float* key   = (const float*)d_in[1];
  const float* value = (const float*)d_in[2];
  const int*   mask  = (const int*)  d_in[3];
  const float* Wq = (const float*)d_in[4];
  const float* bq = (const float*)d_in[5];
  const float* Wk = (const float*)d_in[6];
  const float* bk = (const float*)d_in[7];
  const float* Wv = (const float*)d_in[8];
  const float* bv = (const float*)d_in[9];
  const float* Wo = (const float*)d_in[10];
  const float* bo = (const float*)d_in[11];
  float* out = (float*)d_out;

  const size_t PER = (size_t)2 * S_LEN * DMODEL;   // 4,194,304 elements
  const size_t WSZ = (size_t)DMODEL * DMODEL;      // 262,144

  unsigned short* p = (unsigned short*)d_ws;
  unsigned short* wbuf = p;                        // 4 MB
  unsigned short* xh = p + 8 * WSZ;                // 8 MB (conv input hi / attn out hi)
  unsigned short* xl = xh + PER;                   // 8 MB (conv input lo / attn out lo)
  unsigned short* qfb = xl + PER;                  // 8 MB fp16 Q (log2e-scaled)
  unsigned short* kfb = qfb + PER;                 // 8 MB fp16 K
  unsigned short* vtb = kfb + PER;                 // 8 MB fp16 V^T   (total 44 MB)

  unsigned short* wqh = wbuf + 0 * 2 * WSZ, *wql = wqh + WSZ;
  unsigned short* wkh = wbuf + 1 * 2 * WSZ, *wkl = wkh + WSZ;
  unsigned short* wvh = wbuf + 2 * 2 * WSZ, *wvl = wvh + WSZ;
  unsigned short* woh = wbuf + 3 * 2 * WSZ, *wol = woh + WSZ;

  unsigned long long* bits = (unsigned long long*)d_out;   // overwritten by final GEMM
  pack_mask<<<2048, 256, 0, stream>>>(mask, bits, 2 * S_LEN * NWORDS);
  conv_w4<<<dim3(256, 4), 256, 0, stream>>>(Wq, Wk, Wv, Wo, wbuf);

  dim3 gg(2 * S_LEN / 128, DMODEL / 64);           // (64, 8)
  const int N4 = (int)(PER / 4);

  conv_hilo<<<2048, 256, 0, stream>>>(query, xh, xl, N4);
  gemm_pre<0><<<gg, 256, 0, stream>>>(xh, xl, wqh, wql, bq, qfb, nullptr, 1.44269504f);

  conv_hilo<<<2048, 256, 0, stream>>>(key, xh, xl, N4);
  gemm_pre<0><<<gg, 256, 0, stream>>>(xh, xl, wkh, wkl, bk, kfb, nullptr, 1.0f);

  conv_hilo<<<2048, 256, 0, stream>>>(value, xh, xl, N4);
  gemm_pre<2><<<gg, 256, 0, stream>>>(xh, xl, wvh, wvl, bv, vtb, nullptr, 1.0f);

  attn32<<<1024, 256, 0, stream>>>(qfb, kfb, vtb, bits, xh, xl);

  gemm_pre<1><<<gg, 256, 0, stream>>>(xh, xl, woh, wol, bo, out, nullptr, 1.0f);
}

// Round 10
// 257.091 us; speedup vs baseline: 12.6480x; 1.0685x over previous
//
#include <hip/hip_runtime.h>
#include <hip/hip_bf16.h>
#include <cstddef>
#include <cstdint>

// MultiHeadAttention: B=2, S=4096, D=512, H=8, HD=64
// Round 10: R9 with mask applied BEFORE the row max (bfi blend to -1e9, R6
// numerics). Unmasked-max was numerically unsafe: unscaled scores have
// ~11.5 log2-unit std; masked-out maxima pushed kept fp16 P into subnormals.

#define S_LEN 4096
#define DMODEL 512
#define NHEAD 8
#define HDIM 64
#define NWORDS (S_LEN / 64)

typedef __bf16 bf16x8 __attribute__((ext_vector_type(8)));
typedef _Float16 f16x8 __attribute__((ext_vector_type(8)));
typedef float f32x4 __attribute__((ext_vector_type(4)));
typedef float f32x16 __attribute__((ext_vector_type(16)));
typedef int i32x2 __attribute__((ext_vector_type(2)));
typedef unsigned int u32x4 __attribute__((ext_vector_type(4)));
typedef unsigned short u16x4 __attribute__((ext_vector_type(4)));
typedef unsigned short u16x8 __attribute__((ext_vector_type(8)));

__device__ __forceinline__ unsigned short f2bf(float x) {
  return __builtin_bit_cast(unsigned short, (__bf16)x);
}
__device__ __forceinline__ float bf2f(unsigned short h) {
  union { unsigned u; float f; } v; v.u = ((unsigned)h) << 16; return v.f;
}
__device__ __forceinline__ float fast_exp2(float x) {
#if __has_builtin(__builtin_amdgcn_exp2f)
  return __builtin_amdgcn_exp2f(x);
#else
  return __expf(x * 0.69314718056f);
#endif
}
__device__ __forceinline__ float max3f(float a, float b, float c) {
  return fmaxf(fmaxf(a, b), c);
}
// lane bit as 0/-1 mask
__device__ __forceinline__ int bit_mask(unsigned hs, int bs) {
#if __has_builtin(__builtin_amdgcn_sbfe)
  return __builtin_amdgcn_sbfe((int)hs, bs, 1);
#else
  return ((int)(hs << (31 - bs))) >> 31;
#endif
}
// blend: keep ? x : -1e9   (bfi pattern: (x & msk) | (neg & ~msk))
__device__ __forceinline__ float mask_blend(float x, int msk) {
  const int NEG = __builtin_bit_cast(int, -1.0e9f);
  int xi = __builtin_bit_cast(int, x);
  return __builtin_bit_cast(float, (xi & msk) | (NEG & ~msk));
}
// permlane32_swap: direction on gfx950 verified OPPOSITE to initial assumption
// (R7/R8 failures). Used ONLY for symmetric cross-half reductions, which are
// direction-insensitive.
__device__ __forceinline__ void pl_swap(int& a, int& b) {
#if __has_builtin(__builtin_amdgcn_permlane32_swap)
  i32x2 r = __builtin_amdgcn_permlane32_swap(a, b, false, false);
  a = r[0]; b = r[1];
#else
  asm volatile("v_permlane32_swap_b32 %0, %1" : "+v"(a), "+v"(b));
#endif
}
__device__ __forceinline__ float xhalf_max(float x) {
  int a = __builtin_bit_cast(int, x), b = a;
  pl_swap(a, b);
  return fmaxf(__builtin_bit_cast(float, a), __builtin_bit_cast(float, b));
}
__device__ __forceinline__ float xhalf_sum(float x) {
  int a = __builtin_bit_cast(int, x), b = a;
  pl_swap(a, b);
  return __builtin_bit_cast(float, a) + __builtin_bit_cast(float, b);
}
// swizzled ushort index into a [*][64] 16-bit tile
__device__ __forceinline__ int swzi(int row, int col) {
  return row * 64 + ((col & 7) | ((((col >> 3) ^ row) & 7) << 3));
}

// ---------------------------------------------------------------------------
// fused prep: hi/lo conversions for q,k,v + 4 weights, mask packing. grid (2048,5)
// ---------------------------------------------------------------------------
__global__ __launch_bounds__(256) void prep(
    const float* __restrict__ query, const float* __restrict__ key,
    const float* __restrict__ value,
    const float* __restrict__ w0, const float* __restrict__ w1,
    const float* __restrict__ w2, const float* __restrict__ w3,
    const int* __restrict__ mask,
    unsigned short* __restrict__ qh, unsigned short* __restrict__ ql,
    unsigned short* __restrict__ kh, unsigned short* __restrict__ kl,
    unsigned short* __restrict__ vh, unsigned short* __restrict__ vl,
    unsigned short* __restrict__ wbuf, unsigned long long* __restrict__ bits)
{
  const int task = blockIdx.y;
  const int tid = blockIdx.x * 256 + threadIdx.x;
  const int nthr = gridDim.x * 256;

  if (task < 3) {
    const float* x = (task == 0) ? query : (task == 1) ? key : value;
    unsigned short* h = (task == 0) ? qh : (task == 1) ? kh : vh;
    unsigned short* l = (task == 0) ? ql : (task == 1) ? kl : vl;
    const int n4 = (int)((size_t)2 * S_LEN * DMODEL / 4);
    for (int i = tid; i < n4; i += nthr) {
      float4 f = ((const float4*)x)[i];
      float ff[4] = {f.x, f.y, f.z, f.w};
      u16x4 hh, ll;
      #pragma unroll
      for (int j = 0; j < 4; ++j) {
        unsigned short hb = f2bf(ff[j]);
        hh[j] = hb;
        ll[j] = f2bf(ff[j] - bf2f(hb));
      }
      ((u16x4*)h)[i] = hh;
      ((u16x4*)l)[i] = ll;
    }
  } else if (task == 3) {
    const int per = 65536;
    for (int i = tid; i < 4 * per; i += nthr) {
      int wsel = i >> 16, idx = i & (per - 1);
      const float* src = (wsel == 0) ? w0 : (wsel == 1) ? w1 : (wsel == 2) ? w2 : w3;
      unsigned short* h = wbuf + (size_t)wsel * 2 * 262144;
      unsigned short* l = h + 262144;
      float4 f = ((const float4*)src)[idx];
      float ff[4] = {f.x, f.y, f.z, f.w};
      u16x4 hh, ll;
      #pragma unroll
      for (int j = 0; j < 4; ++j) {
        unsigned short hb = f2bf(ff[j]);
        hh[j] = hb;
        ll[j] = f2bf(ff[j] - bf2f(hb));
      }
      ((u16x4*)h)[idx] = hh;
      ((u16x4*)l)[idx] = ll;
    }
  } else {
    const int nwords = 2 * S_LEN * NWORDS;
    int gw = tid >> 6;
    int lane = threadIdx.x & 63;
    int nw = nthr >> 6;
    for (int w = gw; w < nwords; w += nw) {
      int v = mask[(size_t)w * 64 + lane];
      unsigned long long bm = __ballot(v != 0);
      if (lane == 0) bits[w] = bm;
    }
  }
}

// ---------------------------------------------------------------------------
// GEMM from pre-converted bf16 hi/lo.
// MODE 0: 3-pass, out fp16 head-split [B,H,S,HD], scaled by oscale  (Q,K)
// MODE 1: 1-pass, out f32 flat [N,DMODEL]                           (final)
// MODE 2: 1-pass, out fp16 transposed [B,H,HD,S]                    (V)
// ---------------------------------------------------------------------------
template <int MODE>
__global__ __launch_bounds__(256) void gemm_pre(
    const unsigned short* __restrict__ xh, const unsigned short* __restrict__ xl,
    const unsigned short* __restrict__ wh, const unsigned short* __restrict__ wl,
    const float* __restrict__ bias, void* __restrict__ out0, float oscale)
{
  constexpr bool TRI = (MODE == 0);
  __shared__ __align__(16) unsigned short SMEM[24576];
  unsigned short* Xh = SMEM;
  unsigned short* Xl = SMEM + 8192;
  unsigned short* Wh = SMEM + 16384;
  unsigned short* Wl = SMEM + 20480;

  const int t = threadIdx.x;
  const int lane = t & 63;
  const int w = t >> 6;
  const int c = lane & 15;
  const int g = lane >> 4;
  const int row0 = blockIdx.x * 128;
  const int col0 = blockIdx.y * 64;

  f32x4 acc[2][4];
  #pragma unroll
  for (int mi = 0; mi < 2; ++mi)
    #pragma unroll
    for (int n = 0; n < 4; ++n) acc[mi][n] = (f32x4){0.f, 0.f, 0.f, 0.f};

  u16x8 pxh[4], pxl[4], pwh[2], pwl[2];
  auto issue = [&](int k0) {
    #pragma unroll
    for (int i = 0; i < 4; ++i) {
      int id = i * 256 + t;
      int r = id >> 3, ch = id & 7;
      size_t off = (size_t)(row0 + r) * DMODEL + k0 + ch * 8;
      pxh[i] = *(const u16x8*)(xh + off);
      if (TRI) pxl[i] = *(const u16x8*)(xl + off);
    }
    #pragma unroll
    for (int i = 0; i < 2; ++i) {
      int id = i * 256 + t;
      int r = id >> 3, ch = id & 7;
      size_t off = (size_t)(col0 + r) * DMODEL + k0 + ch * 8;
      pwh[i] = *(const u16x8*)(wh + off);
      if (TRI) pwl[i] = *(const u16x8*)(wl + off);
    }
  };
  auto commit = [&]() {
    #pragma unroll
    for (int i = 0; i < 4; ++i) {
      int id = i * 256 + t;
      int r = id >> 3, ch = id & 7;
      int dst = r * 64 + (((ch ^ r) & 7) << 3);
      *(u16x8*)&Xh[dst] = pxh[i];
      if (TRI) *(u16x8*)&Xl[dst] = pxl[i];
    }
    #pragma unroll
    for (int i = 0; i < 2; ++i) {
      int id = i * 256 + t;
      int r = id >> 3, ch = id & 7;
      int dst = r * 64 + (((ch ^ r) & 7) << 3);
      *(u16x8*)&Wh[dst] = pwh[i];
      if (TRI) *(u16x8*)&Wl[dst] = pwl[i];
    }
  };

  issue(0);
  commit();
  __syncthreads();

  for (int k0 = 0; k0 < DMODEL; k0 += 64) {
    const bool more = (k0 + 64) < DMODEL;
    if (more) issue(k0 + 64);

    #pragma unroll
    for (int kk = 0; kk < 2; ++kk) {
      bf16x8 ah[2], al[2], bh_[4], bl_[4];
      #pragma unroll
      for (int mi = 0; mi < 2; ++mi) {
        int r = w * 32 + mi * 16 + c;
        ah[mi] = __builtin_bit_cast(bf16x8, *(const u16x8*)&Xh[swzi(r, (kk * 4 + g) * 8)]);
        if (TRI) al[mi] = __builtin_bit_cast(bf16x8, *(const u16x8*)&Xl[swzi(r, (kk * 4 + g) * 8)]);
      }
      #pragma unroll
      for (int n = 0; n < 4; ++n) {
        int r = n * 16 + c;
        bh_[n] = __builtin_bit_cast(bf16x8, *(const u16x8*)&Wh[swzi(r, (kk * 4 + g) * 8)]);
        if (TRI) bl_[n] = __builtin_bit_cast(bf16x8, *(const u16x8*)&Wl[swzi(r, (kk * 4 + g) * 8)]);
      }
      #pragma unroll
      for (int mi = 0; mi < 2; ++mi)
        #pragma unroll
        for (int n = 0; n < 4; ++n) {
          acc[mi][n] = __builtin_amdgcn_mfma_f32_16x16x32_bf16(ah[mi], bh_[n], acc[mi][n], 0, 0, 0);
          if (TRI) {
            acc[mi][n] = __builtin_amdgcn_mfma_f32_16x16x32_bf16(al[mi], bh_[n], acc[mi][n], 0, 0, 0);
            acc[mi][n] = __builtin_amdgcn_mfma_f32_16x16x32_bf16(ah[mi], bl_[n], acc[mi][n], 0, 0, 0);
          }
        }
    }
    __syncthreads();
    if (more) {
      commit();
      __syncthreads();
    }
  }

  if (MODE == 0) {
    unsigned short* Yf = (unsigned short*)out0;
    #pragma unroll
    for (int mi = 0; mi < 2; ++mi)
      #pragma unroll
      for (int n = 0; n < 4; ++n)
        #pragma unroll
        for (int j = 0; j < 4; ++j) {
          int rr = row0 + w * 32 + mi * 16 + g * 4 + j;
          int oo = col0 + n * 16 + c;
          float val = (acc[mi][n][j] + bias[oo]) * oscale;
          int bb = rr >> 12, ss = rr & (S_LEN - 1), h2 = oo >> 6, hd = oo & 63;
          size_t idx = (((size_t)(bb * NHEAD + h2)) * S_LEN + ss) * HDIM + hd;
          Yf[idx] = __builtin_bit_cast(unsigned short, (_Float16)val);
        }
  } else if (MODE == 1) {
    float* Y = (float*)out0;
    #pragma unroll
    for (int mi = 0; mi < 2; ++mi)
      #pragma unroll
      for (int n = 0; n < 4; ++n)
        #pragma unroll
        for (int j = 0; j < 4; ++j) {
          int rr = row0 + w * 32 + mi * 16 + g * 4 + j;
          int oo = col0 + n * 16 + c;
          Y[(size_t)rr * DMODEL + oo] = acc[mi][n][j] + bias[oo];
        }
  } else {
    unsigned short* Ts = SMEM;   // [128][68] fp16
    __syncthreads();
    #pragma unroll
    for (int mi = 0; mi < 2; ++mi)
      #pragma unroll
      for (int n = 0; n < 4; ++n)
        #pragma unroll
        for (int j = 0; j < 4; ++j) {
          int r = w * 32 + mi * 16 + g * 4 + j;
          int o = n * 16 + c;
          Ts[r * 68 + o] = __builtin_bit_cast(unsigned short, (_Float16)(acc[mi][n][j] + bias[col0 + o]));
        }
    __syncthreads();
    unsigned short* vt = (unsigned short*)out0;
    int bb = row0 >> 12, sbase = row0 & (S_LEN - 1), h2 = col0 >> 6;
    int d = t >> 2, s0 = (t & 3) * 32;
    size_t obase = ((size_t)((bb * NHEAD + h2) * HDIM + d)) * S_LEN + sbase + s0;
    #pragma unroll
    for (int i = 0; i < 4; ++i) {
      u16x8 v;
      #pragma unroll
      for (int jj = 0; jj < 8; ++jj) v[jj] = Ts[(s0 + i * 8 + jj) * 68 + d];
      *(u16x8*)(vt + obase + i * 8) = v;
    }
  }
}

// ---------------------------------------------------------------------------
// Flash attention on 32x32x16 fp16 MFMA, swapped operands, exp2 domain.
// ---------------------------------------------------------------------------
__global__ __launch_bounds__(256) void attn32(
    const unsigned short* __restrict__ qf, const unsigned short* __restrict__ kf,
    const unsigned short* __restrict__ vt, const unsigned long long* __restrict__ mbits,
    unsigned short* __restrict__ Ob)
{
  __shared__ __align__(16) unsigned short LDS[2][2][4096];   // 32 KB

  const int t = threadIdx.x;
  const int lane = t & 63;
  const int w = t >> 6;
  const int pair = w >> 1;
  const int chunk = w & 1;
  const int c31 = lane & 31;
  const int hi = lane >> 5;

  const int nwg = gridDim.x;
  const int bid = blockIdx.x;
  const int lin = (bid & 7) * (nwg >> 3) + (bid >> 3);
  const int qi = lin & 63;
  const int bh = lin >> 6;
  const int q0 = qi * 64;
  const int b = bh >> 3, h = bh & 7;
  const int qrow = q0 + pair * 32 + c31;

  const unsigned short* Qp = qf + ((size_t)bh * S_LEN + qrow) * HDIM;
  f16x8 qfr[4];
  #pragma unroll
  for (int s = 0; s < 4; ++s)
    qfr[s] = __builtin_bit_cast(f16x8, *(const u16x8*)(Qp + 16 * s + 8 * hi));

  const unsigned short* Kb = kf + (size_t)bh * S_LEN * HDIM;
  const unsigned short* Vbt = vt + (size_t)bh * HDIM * S_LEN;
  const unsigned long long* mptr = mbits + (size_t)(b * S_LEN + qrow) * NWORDS;

  const int sr0 = t >> 3, sch = t & 7;
  const int sr1 = sr0 + 32;
  const int dst0 = sr0 * 64 + (((sch ^ sr0) & 7) << 3);
  const int dst1 = sr1 * 64 + (((sch ^ sr1) & 7) << 3);
  u16x8 pkk[2], pkv[2];
  auto issue = [&](int k0) {
    pkk[0] = *(const u16x8*)(Kb + (size_t)(k0 + sr0) * HDIM + sch * 8);
    pkk[1] = *(const u16x8*)(Kb + (size_t)(k0 + sr1) * HDIM + sch * 8);
    pkv[0] = *(const u16x8*)(Vbt + (size_t)sr0 * S_LEN + k0 + sch * 8);
    pkv[1] = *(const u16x8*)(Vbt + (size_t)sr1 * S_LEN + k0 + sch * 8);
  };
  auto commit = [&](int buf) {
    *(u16x8*)&LDS[buf][0][dst0] = pkk[0];
    *(u16x8*)&LDS[buf][0][dst1] = pkk[1];
    *(u16x8*)&LDS[buf][1][dst0] = pkv[0];
    *(u16x8*)&LDS[buf][1][dst1] = pkv[1];
  };

  f32x16 oacc0, oacc1;
  #pragma unroll
  for (int r = 0; r < 16; ++r) { oacc0[r] = 0.f; oacc1[r] = 0.f; }
  const f32x16 fzero = oacc0;
  float mrow = -INFINITY, lrow = 0.f;

  unsigned long long m64 = mptr[0], m64n = 0;

  issue(0);
  commit(0);
  __syncthreads();

  int cur = 0;
  for (int kt = 0; kt < S_LEN / 64; ++kt) {
    const bool more = kt < (S_LEN / 64 - 1);
    if (more) {
      issue((kt + 1) * 64);
      m64n = mptr[kt + 1];
    }
    const unsigned short* K_ = &LDS[cur][0][0];
    const unsigned short* Vt_ = &LDS[cur][1][0];

    // ---- scores (single fp16 pass) ----
    f32x16 p;
    __builtin_amdgcn_s_setprio(1);
    {
      int idx = swzi(chunk * 32 + c31, 8 * hi);
      f16x8 kfr = __builtin_bit_cast(f16x8, *(const u16x8*)&K_[idx]);
      p = __builtin_amdgcn_mfma_f32_32x32x16_f16(kfr, qfr[0], fzero, 0, 0, 0);
    }
    #pragma unroll
    for (int s = 1; s < 4; ++s) {
      int idx = swzi(chunk * 32 + c31, 16 * s + 8 * hi);
      f16x8 kfr = __builtin_bit_cast(f16x8, *(const u16x8*)&K_[idx]);
      p = __builtin_amdgcn_mfma_f32_32x32x16_f16(kfr, qfr[s], p, 0, 0, 0);
    }
    __builtin_amdgcn_s_setprio(0);

    // ---- mask BEFORE max: blend masked scores to -1e9 (bfi) ----
    unsigned half = chunk ? (unsigned)(m64 >> 32) : (unsigned)m64;
    unsigned hs = half >> (hi * 4);
    #pragma unroll
    for (int r = 0; r < 16; ++r) {
      int bs = (r & 3) + 8 * (r >> 2);
      p[r] = mask_blend(p[r], bit_mask(hs, bs));
    }

    // ---- masked row max ----
    float t0 = max3f(p[0], p[1], p[2]);
    float t1 = max3f(p[3], p[4], p[5]);
    float t2 = max3f(p[6], p[7], p[8]);
    float t3 = max3f(p[9], p[10], p[11]);
    float t4 = max3f(p[12], p[13], p[14]);
    float mx = fmaxf(max3f(t0, t1, t2), max3f(t3, t4, p[15]));
    mx = xhalf_max(mx);

    float mn, scl;
    if (__all(mx <= mrow + 11.54f)) {    // defer-max
      mn = mrow;
      scl = 1.0f;
    } else {
      mn = fmaxf(mrow, mx);
      scl = fast_exp2(mrow - mn);
      mrow = mn;
      oacc0 *= scl;
      oacc1 *= scl;
    }

    // ---- exp2 (masked entries -> exp2(-huge) = 0 naturally) ----
    #pragma unroll
    for (int r = 0; r < 16; ++r) p[r] = fast_exp2(p[r] - mn);

    float s0_ = (p[0] + p[1]) + (p[2] + p[3]);
    float s1_ = (p[4] + p[5]) + (p[6] + p[7]);
    float s2_ = (p[8] + p[9]) + (p[10] + p[11]);
    float s3_ = (p[12] + p[13]) + (p[14] + p[15]);
    float ps = xhalf_sum((s0_ + s1_) + (s2_ + s3_));
    lrow = lrow * scl + ps;

    // ---- P redistribution: R6-verified shfl_xor keep/send/recv pattern ----
    unsigned W[4][2];
    #pragma unroll
    for (int rq = 0; rq < 4; ++rq) {
      W[rq][0] = __builtin_bit_cast(unsigned, __builtin_amdgcn_cvt_pkrtz(p[4 * rq + 0], p[4 * rq + 1]));
      W[rq][1] = __builtin_bit_cast(unsigned, __builtin_amdgcn_cvt_pkrtz(p[4 * rq + 2], p[4 * rq + 3]));
    }
    f16x8 pf[2];
    #pragma unroll
    for (int s2 = 0; s2 < 2; ++s2) {
      unsigned keep0 = hi ? W[2 * s2 + 1][0] : W[2 * s2][0];
      unsigned keep1 = hi ? W[2 * s2 + 1][1] : W[2 * s2][1];
      unsigned send0 = hi ? W[2 * s2][0] : W[2 * s2 + 1][0];
      unsigned send1 = hi ? W[2 * s2][1] : W[2 * s2 + 1][1];
      unsigned recv0 = (unsigned)__shfl_xor((int)send0, 32, 64);
      unsigned recv1 = (unsigned)__shfl_xor((int)send1, 32, 64);
      u32x4 fw;
      fw[0] = hi ? recv0 : keep0;
      fw[1] = hi ? recv1 : keep1;
      fw[2] = hi ? keep0 : recv0;
      fw[3] = hi ? keep1 : recv1;
      pf[s2] = __builtin_bit_cast(f16x8, fw);
    }

    // ---- PV ----
    __builtin_amdgcn_s_setprio(1);
    #pragma unroll
    for (int s2 = 0; s2 < 2; ++s2) {
      int col = chunk * 32 + 16 * s2 + 8 * hi;
      f16x8 vf0 = __builtin_bit_cast(f16x8, *(const u16x8*)&Vt_[swzi(c31, col)]);
      f16x8 vf1 = __builtin_bit_cast(f16x8, *(const u16x8*)&Vt_[swzi(32 + c31, col)]);
      oacc0 = __builtin_amdgcn_mfma_f32_32x32x16_f16(vf0, pf[s2], oacc0, 0, 0, 0);
      oacc1 = __builtin_amdgcn_mfma_f32_32x32x16_f16(vf1, pf[s2], oacc1, 0, 0, 0);
    }
    __builtin_amdgcn_s_setprio(0);

    if (more) {
      m64 = m64n;
      commit(cur ^ 1);
    }
    __syncthreads();
    cur ^= 1;
  }

  // ---- flash merge across the wave pair, via LDS ----
  float* mb = (float*)&LDS[0][0][0];   // [2 pair][2 hi][32 c31][36]
  const int mi = ((pair * 2 + hi) * 32 + c31) * 36;
  if (chunk == 1) {
    #pragma unroll
    for (int q4 = 0; q4 < 4; ++q4) {
      *(f32x4*)&mb[mi + q4 * 4]      = (f32x4){oacc0[q4 * 4], oacc0[q4 * 4 + 1], oacc0[q4 * 4 + 2], oacc0[q4 * 4 + 3]};
      *(f32x4*)&mb[mi + 16 + q4 * 4] = (f32x4){oacc1[q4 * 4], oacc1[q4 * 4 + 1], oacc1[q4 * 4 + 2], oacc1[q4 * 4 + 3]};
    }
    mb[mi + 32] = mrow;
    mb[mi + 33] = lrow;
  }
  __syncthreads();
  if (chunk == 0) {
    float m1 = mb[mi + 32], l1 = mb[mi + 33];
    float mS = fmaxf(mrow, m1);
    float f0 = fast_exp2(mrow - mS), f1 = fast_exp2(m1 - mS);
    float lS = lrow * f0 + l1 * f1;
    float inv = 1.0f / lS;
    size_t obase = ((size_t)b * S_LEN + qrow) * DMODEL + h * HDIM;
    #pragma unroll
    for (int c2 = 0; c2 < 2; ++c2) {
      #pragma unroll
      for (int rq = 0; rq < 4; ++rq) {
        u16x4 hv;
        #pragma unroll
        for (int rb = 0; rb < 4; ++rb) {
          int reg = 4 * rq + rb;
          float o0 = (c2 == 0) ? oacc0[reg] : oacc1[reg];
          float o1 = mb[mi + c2 * 16 + reg];
          hv[rb] = f2bf((o0 * f0 + o1 * f1) * inv);
        }
        *(u16x4*)(Ob + obase + 32 * c2 + 8 * rq + 4 * hi) = hv;
      }
    }
  }
}

// ---------------------------------------------------------------------------
extern "C" void kernel_launch(void* const* d_in, const int* in_sizes, int n_in,
                              void* d_out, int out_size, void* d_ws, size_t ws_size,
                              hipStream_t stream) {
  const float* query = (const float*)d_in[0];
  const float* key   = (const float*)d_in[1];
  const float* value = (const float*)d_in[2];
  const int*   mask  = (const int*)  d_in[3];
  const float* Wq = (const float*)d_in[4];
  const float* bq = (const float*)d_in[5];
  const float* Wk = (const float*)d_in[6];
  const float* bk = (const float*)d_in[7];
  const float* Wv = (const float*)d_in[8];
  const float* bv = (const float*)d_in[9];
  const float* Wo = (const float*)d_in[10];
  const float* bo = (const float*)d_in[11];
  float* out = (float*)d_out;

  const size_t PER = (size_t)2 * S_LEN * DMODEL;   // 4,194,304 elements
  const size_t WSZ = (size_t)DMODEL * DMODEL;      // 262,144

  unsigned short* p = (unsigned short*)d_ws;
  unsigned short* wbuf = p;                        // 4 MB
  unsigned short* xh = p + 8 * WSZ;
  unsigned short* xl = xh + PER;
  unsigned short* yh = xl + PER;
  unsigned short* yl = yh + PER;
  unsigned short* zh = yl + PER;
  unsigned short* zl = zh + PER;
  unsigned short* qfb = zl + PER;
  unsigned short* kfb = qfb + PER;
  unsigned short* vtb = kfb + PER;                 // total 76 MB

  unsigned short* wqh = wbuf + 0 * 2 * WSZ, *wql = wqh + WSZ;
  unsigned short* wkh = wbuf + 1 * 2 * WSZ, *wkl = wkh + WSZ;
  unsigned short* wvh = wbuf + 2 * 2 * WSZ, *wvl = wvh + WSZ;
  unsigned short* woh = wbuf + 3 * 2 * WSZ;

  unsigned long long* bits = (unsigned long long*)d_out;

  prep<<<dim3(2048, 5), 256, 0, stream>>>(query, key, value, Wq, Wk, Wv, Wo, mask,
                                          xh, xl, yh, yl, zh, zl, wbuf, bits);

  dim3 gg(2 * S_LEN / 128, DMODEL / 64);           // (64, 8)
  gemm_pre<0><<<gg, 256, 0, stream>>>(xh, xl, wqh, wql, bq, qfb, 1.44269504f);
  gemm_pre<0><<<gg, 256, 0, stream>>>(yh, yl, wkh, wkl, bk, kfb, 1.0f);
  gemm_pre<2><<<gg, 256, 0, stream>>>(zh, zl, wvh, wvl, bv, vtb, 1.0f);

  attn32<<<1024, 256, 0, stream>>>(qfb, kfb, vtb, bits, xh);

  gemm_pre<1><<<gg, 256, 0, stream>>>(xh, nullptr, woh, nullptr, bo, out, 1.0f);
}

// Round 11
// 246.265 us; speedup vs baseline: 13.2040x; 1.0440x over previous
//
#include <hip/hip_runtime.h>
#include <hip/hip_bf16.h>
#include <cstddef>
#include <cstdint>

// MultiHeadAttention: B=2, S=4096, D=512, H=8, HD=64
// Round 11: attn staging via global_load_lds (linear LDS dest + inverse-swizzled
// global source, one barrier/tile); Q/K/V projections fused into one launch.
// Numerics identical to R10 (passed, absmax 0.0156).

#define S_LEN 4096
#define DMODEL 512
#define NHEAD 8
#define HDIM 64
#define NWORDS (S_LEN / 64)

typedef __bf16 bf16x8 __attribute__((ext_vector_type(8)));
typedef _Float16 f16x8 __attribute__((ext_vector_type(8)));
typedef float f32x4 __attribute__((ext_vector_type(4)));
typedef float f32x16 __attribute__((ext_vector_type(16)));
typedef int i32x2 __attribute__((ext_vector_type(2)));
typedef unsigned int u32x4 __attribute__((ext_vector_type(4)));
typedef unsigned short u16x4 __attribute__((ext_vector_type(4)));
typedef unsigned short u16x8 __attribute__((ext_vector_type(8)));

__device__ __forceinline__ unsigned short f2bf(float x) {
  return __builtin_bit_cast(unsigned short, (__bf16)x);
}
__device__ __forceinline__ float bf2f(unsigned short h) {
  union { unsigned u; float f; } v; v.u = ((unsigned)h) << 16; return v.f;
}
__device__ __forceinline__ float fast_exp2(float x) {
#if __has_builtin(__builtin_amdgcn_exp2f)
  return __builtin_amdgcn_exp2f(x);
#else
  return __expf(x * 0.69314718056f);
#endif
}
__device__ __forceinline__ float max3f(float a, float b, float c) {
  return fmaxf(fmaxf(a, b), c);
}
__device__ __forceinline__ int bit_mask(unsigned hs, int bs) {
#if __has_builtin(__builtin_amdgcn_sbfe)
  return __builtin_amdgcn_sbfe((int)hs, bs, 1);
#else
  return ((int)(hs << (31 - bs))) >> 31;
#endif
}
// keep ? x : -1e9  (bfi)
__device__ __forceinline__ float mask_blend(float x, int msk) {
  const int NEG = __builtin_bit_cast(int, -1.0e9f);
  int xi = __builtin_bit_cast(int, x);
  return __builtin_bit_cast(float, (xi & msk) | (NEG & ~msk));
}
// permlane32_swap: gfx950 direction verified opposite to initial assumption
// (R7/R8). Only used for symmetric (direction-insensitive) reductions.
__device__ __forceinline__ void pl_swap(int& a, int& b) {
#if __has_builtin(__builtin_amdgcn_permlane32_swap)
  i32x2 r = __builtin_amdgcn_permlane32_swap(a, b, false, false);
  a = r[0]; b = r[1];
#else
  asm volatile("v_permlane32_swap_b32 %0, %1" : "+v"(a), "+v"(b));
#endif
}
__device__ __forceinline__ float xhalf_max(float x) {
  int a = __builtin_bit_cast(int, x), b = a;
  pl_swap(a, b);
  return fmaxf(__builtin_bit_cast(float, a), __builtin_bit_cast(float, b));
}
__device__ __forceinline__ float xhalf_sum(float x) {
  int a = __builtin_bit_cast(int, x), b = a;
  pl_swap(a, b);
  return __builtin_bit_cast(float, a) + __builtin_bit_cast(float, b);
}
// swizzled ushort index into a [*][64] 16-bit tile
__device__ __forceinline__ int swzi(int row, int col) {
  return row * 64 + ((col & 7) | ((((col >> 3) ^ row) & 7) << 3));
}
// async global->LDS, 16B per lane; LDS dest = lds + lane*16B (wave-uniform base)
__device__ __forceinline__ void gload16(const unsigned short* g, unsigned short* lds) {
  __builtin_amdgcn_global_load_lds(
      (const __attribute__((address_space(1))) unsigned int*)g,
      (__attribute__((address_space(3))) unsigned int*)lds, 16, 0, 0);
}

// ---------------------------------------------------------------------------
// fused prep: hi/lo conversions for q,k,v + 4 weights, mask packing. grid (2048,5)
// ---------------------------------------------------------------------------
__global__ __launch_bounds__(256) void prep(
    const float* __restrict__ query, const float* __restrict__ key,
    const float* __restrict__ value,
    const float* __restrict__ w0, const float* __restrict__ w1,
    const float* __restrict__ w2, const float* __restrict__ w3,
    const int* __restrict__ mask,
    unsigned short* __restrict__ qh, unsigned short* __restrict__ ql,
    unsigned short* __restrict__ kh, unsigned short* __restrict__ kl,
    unsigned short* __restrict__ vh, unsigned short* __restrict__ vl,
    unsigned short* __restrict__ wbuf, unsigned long long* __restrict__ bits)
{
  const int task = blockIdx.y;
  const int tid = blockIdx.x * 256 + threadIdx.x;
  const int nthr = gridDim.x * 256;

  if (task < 3) {
    const float* x = (task == 0) ? query : (task == 1) ? key : value;
    unsigned short* h = (task == 0) ? qh : (task == 1) ? kh : vh;
    unsigned short* l = (task == 0) ? ql : (task == 1) ? kl : vl;
    const int n4 = (int)((size_t)2 * S_LEN * DMODEL / 4);
    for (int i = tid; i < n4; i += nthr) {
      float4 f = ((const float4*)x)[i];
      float ff[4] = {f.x, f.y, f.z, f.w};
      u16x4 hh, ll;
      #pragma unroll
      for (int j = 0; j < 4; ++j) {
        unsigned short hb = f2bf(ff[j]);
        hh[j] = hb;
        ll[j] = f2bf(ff[j] - bf2f(hb));
      }
      ((u16x4*)h)[i] = hh;
      ((u16x4*)l)[i] = ll;
    }
  } else if (task == 3) {
    const int per = 65536;
    for (int i = tid; i < 4 * per; i += nthr) {
      int wsel = i >> 16, idx = i & (per - 1);
      const float* src = (wsel == 0) ? w0 : (wsel == 1) ? w1 : (wsel == 2) ? w2 : w3;
      unsigned short* h = wbuf + (size_t)wsel * 2 * 262144;
      unsigned short* l = h + 262144;
      float4 f = ((const float4*)src)[idx];
      float ff[4] = {f.x, f.y, f.z, f.w};
      u16x4 hh, ll;
      #pragma unroll
      for (int j = 0; j < 4; ++j) {
        unsigned short hb = f2bf(ff[j]);
        hh[j] = hb;
        ll[j] = f2bf(ff[j] - bf2f(hb));
      }
      ((u16x4*)h)[idx] = hh;
      ((u16x4*)l)[idx] = ll;
    }
  } else {
    const int nwords = 2 * S_LEN * NWORDS;
    int gw = tid >> 6;
    int lane = threadIdx.x & 63;
    int nw = nthr >> 6;
    for (int w = gw; w < nwords; w += nw) {
      int v = mask[(size_t)w * 64 + lane];
      unsigned long long bm = __ballot(v != 0);
      if (lane == 0) bits[w] = bm;
    }
  }
}

// ---------------------------------------------------------------------------
// Fused Q/K/V projections in one launch. blockIdx.z = mode:
//  0: Q = xq @ Wq^T + bq   (3-pass hi/lo, out fp16 head-split, *log2e)
//  1: K = xk @ Wk^T + bk   (3-pass hi/lo, out fp16 head-split)
//  2: V = xv @ Wv^T + bv   (1-pass,       out fp16 transposed [B,H,HD,S])
// ---------------------------------------------------------------------------
__global__ __launch_bounds__(256) void proj_qkv(
    const unsigned short* __restrict__ qxh, const unsigned short* __restrict__ qxl,
    const unsigned short* __restrict__ kxh, const unsigned short* __restrict__ kxl,
    const unsigned short* __restrict__ vxh, const unsigned short* __restrict__ vxl,
    const unsigned short* __restrict__ wbuf,
    const float* __restrict__ bq, const float* __restrict__ bk, const float* __restrict__ bv,
    unsigned short* __restrict__ qout, unsigned short* __restrict__ kout,
    unsigned short* __restrict__ vout)
{
  const int mode = blockIdx.z;
  const bool tri = (mode < 2);
  const unsigned short* xh = (mode == 0) ? qxh : (mode == 1) ? kxh : vxh;
  const unsigned short* xl = (mode == 0) ? qxl : (mode == 1) ? kxl : vxl;
  const unsigned short* wh = wbuf + (size_t)mode * 2 * 262144;
  const unsigned short* wl = wh + 262144;
  const float* bias = (mode == 0) ? bq : (mode == 1) ? bk : bv;
  unsigned short* out = (mode == 0) ? qout : (mode == 1) ? kout : vout;
  const float oscale = (mode == 0) ? 1.44269504f : 1.0f;

  __shared__ __align__(16) unsigned short SMEM[24576];
  unsigned short* Xh = SMEM;
  unsigned short* Xl = SMEM + 8192;
  unsigned short* Wh = SMEM + 16384;
  unsigned short* Wl = SMEM + 20480;

  const int t = threadIdx.x;
  const int lane = t & 63;
  const int w = t >> 6;
  const int c = lane & 15;
  const int g = lane >> 4;
  const int row0 = blockIdx.x * 128;
  const int col0 = blockIdx.y * 64;

  f32x4 acc[2][4];
  #pragma unroll
  for (int mi = 0; mi < 2; ++mi)
    #pragma unroll
    for (int n = 0; n < 4; ++n) acc[mi][n] = (f32x4){0.f, 0.f, 0.f, 0.f};

  u16x8 pxh[4], pxl[4], pwh[2], pwl[2];
  auto issue = [&](int k0) {
    #pragma unroll
    for (int i = 0; i < 4; ++i) {
      int id = i * 256 + t;
      int r = id >> 3, ch = id & 7;
      size_t off = (size_t)(row0 + r) * DMODEL + k0 + ch * 8;
      pxh[i] = *(const u16x8*)(xh + off);
      if (tri) pxl[i] = *(const u16x8*)(xl + off);
    }
    #pragma unroll
    for (int i = 0; i < 2; ++i) {
      int id = i * 256 + t;
      int r = id >> 3, ch = id & 7;
      size_t off = (size_t)(col0 + r) * DMODEL + k0 + ch * 8;
      pwh[i] = *(const u16x8*)(wh + off);
      if (tri) pwl[i] = *(const u16x8*)(wl + off);
    }
  };
  auto commit = [&]() {
    #pragma unroll
    for (int i = 0; i < 4; ++i) {
      int id = i * 256 + t;
      int r = id >> 3, ch = id & 7;
      int dst = r * 64 + (((ch ^ r) & 7) << 3);
      *(u16x8*)&Xh[dst] = pxh[i];
      if (tri) *(u16x8*)&Xl[dst] = pxl[i];
    }
    #pragma unroll
    for (int i = 0; i < 2; ++i) {
      int id = i * 256 + t;
      int r = id >> 3, ch = id & 7;
      int dst = r * 64 + (((ch ^ r) & 7) << 3);
      *(u16x8*)&Wh[dst] = pwh[i];
      if (tri) *(u16x8*)&Wl[dst] = pwl[i];
    }
  };

  issue(0);
  commit();
  __syncthreads();

  for (int k0 = 0; k0 < DMODEL; k0 += 64) {
    const bool more = (k0 + 64) < DMODEL;
    if (more) issue(k0 + 64);

    #pragma unroll
    for (int kk = 0; kk < 2; ++kk) {
      bf16x8 ah[2], al[2], bh_[4], bl_[4];
      #pragma unroll
      for (int mi = 0; mi < 2; ++mi) {
        int r = w * 32 + mi * 16 + c;
        ah[mi] = __builtin_bit_cast(bf16x8, *(const u16x8*)&Xh[swzi(r, (kk * 4 + g) * 8)]);
        if (tri) al[mi] = __builtin_bit_cast(bf16x8, *(const u16x8*)&Xl[swzi(r, (kk * 4 + g) * 8)]);
      }
      #pragma unroll
      for (int n = 0; n < 4; ++n) {
        int r = n * 16 + c;
        bh_[n] = __builtin_bit_cast(bf16x8, *(const u16x8*)&Wh[swzi(r, (kk * 4 + g) * 8)]);
        if (tri) bl_[n] = __builtin_bit_cast(bf16x8, *(const u16x8*)&Wl[swzi(r, (kk * 4 + g) * 8)]);
      }
      #pragma unroll
      for (int mi = 0; mi < 2; ++mi)
        #pragma unroll
        for (int n = 0; n < 4; ++n) {
          acc[mi][n] = __builtin_amdgcn_mfma_f32_16x16x32_bf16(ah[mi], bh_[n], acc[mi][n], 0, 0, 0);
          if (tri) {
            acc[mi][n] = __builtin_amdgcn_mfma_f32_16x16x32_bf16(al[mi], bh_[n], acc[mi][n], 0, 0, 0);
            acc[mi][n] = __builtin_amdgcn_mfma_f32_16x16x32_bf16(ah[mi], bl_[n], acc[mi][n], 0, 0, 0);
          }
        }
    }
    __syncthreads();
    if (more) {
      commit();
      __syncthreads();
    }
  }

  if (mode < 2) {
    #pragma unroll
    for (int mi = 0; mi < 2; ++mi)
      #pragma unroll
      for (int n = 0; n < 4; ++n)
        #pragma unroll
        for (int j = 0; j < 4; ++j) {
          int rr = row0 + w * 32 + mi * 16 + g * 4 + j;
          int oo = col0 + n * 16 + c;
          float val = (acc[mi][n][j] + bias[oo]) * oscale;
          int bb = rr >> 12, ss = rr & (S_LEN - 1), h2 = oo >> 6, hd = oo & 63;
          size_t idx = (((size_t)(bb * NHEAD + h2)) * S_LEN + ss) * HDIM + hd;
          out[idx] = __builtin_bit_cast(unsigned short, (_Float16)val);
        }
  } else {
    unsigned short* Ts = SMEM;   // [128][68] fp16
    __syncthreads();
    #pragma unroll
    for (int mi = 0; mi < 2; ++mi)
      #pragma unroll
      for (int n = 0; n < 4; ++n)
        #pragma unroll
        for (int j = 0; j < 4; ++j) {
          int r = w * 32 + mi * 16 + g * 4 + j;
          int o = n * 16 + c;
          Ts[r * 68 + o] = __builtin_bit_cast(unsigned short, (_Float16)(acc[mi][n][j] + bias[col0 + o]));
        }
    __syncthreads();
    int bb = row0 >> 12, sbase = row0 & (S_LEN - 1), h2 = col0 >> 6;
    int d = t >> 2, s0 = (t & 3) * 32;
    size_t obase = ((size_t)((bb * NHEAD + h2) * HDIM + d)) * S_LEN + sbase + s0;
    #pragma unroll
    for (int i = 0; i < 4; ++i) {
      u16x8 v;
      #pragma unroll
      for (int jj = 0; jj < 8; ++jj) v[jj] = Ts[(s0 + i * 8 + jj) * 68 + d];
      *(u16x8*)(out + obase + i * 8) = v;
    }
  }
}

// ---------------------------------------------------------------------------
// Final projection GEMM (1-pass, f32 out flat)
// ---------------------------------------------------------------------------
__global__ __launch_bounds__(256) void gemm_out(
    const unsigned short* __restrict__ xh, const unsigned short* __restrict__ wh,
    const float* __restrict__ bias, float* __restrict__ Y)
{
  __shared__ __align__(16) unsigned short SMEM[24576];
  unsigned short* Xh = SMEM;
  unsigned short* Wh = SMEM + 16384;

  const int t = threadIdx.x;
  const int lane = t & 63;
  const int w = t >> 6;
  const int c = lane & 15;
  const int g = lane >> 4;
  const int row0 = blockIdx.x * 128;
  const int col0 = blockIdx.y * 64;

  f32x4 acc[2][4];
  #pragma unroll
  for (int mi = 0; mi < 2; ++mi)
    #pragma unroll
    for (int n = 0; n < 4; ++n) acc[mi][n] = (f32x4){0.f, 0.f, 0.f, 0.f};

  u16x8 pxh[4], pwh[2];
  auto issue = [&](int k0) {
    #pragma unroll
    for (int i = 0; i < 4; ++i) {
      int id = i * 256 + t;
      int r = id >> 3, ch = id & 7;
      pxh[i] = *(const u16x8*)(xh + (size_t)(row0 + r) * DMODEL + k0 + ch * 8);
    }
    #pragma unroll
    for (int i = 0; i < 2; ++i) {
      int id = i * 256 + t;
      int r = id >> 3, ch = id & 7;
      pwh[i] = *(const u16x8*)(wh + (size_t)(col0 + r) * DMODEL + k0 + ch * 8);
    }
  };
  auto commit = [&]() {
    #pragma unroll
    for (int i = 0; i < 4; ++i) {
      int id = i * 256 + t;
      int r = id >> 3, ch = id & 7;
      *(u16x8*)&Xh[r * 64 + (((ch ^ r) & 7) << 3)] = pxh[i];
    }
    #pragma unroll
    for (int i = 0; i < 2; ++i) {
      int id = i * 256 + t;
      int r = id >> 3, ch = id & 7;
      *(u16x8*)&Wh[r * 64 + (((ch ^ r) & 7) << 3)] = pwh[i];
    }
  };

  issue(0);
  commit();
  __syncthreads();

  for (int k0 = 0; k0 < DMODEL; k0 += 64) {
    const bool more = (k0 + 64) < DMODEL;
    if (more) issue(k0 + 64);

    #pragma unroll
    for (int kk = 0; kk < 2; ++kk) {
      bf16x8 ah[2], bh_[4];
      #pragma unroll
      for (int mi = 0; mi < 2; ++mi)
        ah[mi] = __builtin_bit_cast(bf16x8, *(const u16x8*)&Xh[swzi(w * 32 + mi * 16 + c, (kk * 4 + g) * 8)]);
      #pragma unroll
      for (int n = 0; n < 4; ++n)
        bh_[n] = __builtin_bit_cast(bf16x8, *(const u16x8*)&Wh[swzi(n * 16 + c, (kk * 4 + g) * 8)]);
      #pragma unroll
      for (int mi = 0; mi < 2; ++mi)
        #pragma unroll
        for (int n = 0; n < 4; ++n)
          acc[mi][n] = __builtin_amdgcn_mfma_f32_16x16x32_bf16(ah[mi], bh_[n], acc[mi][n], 0, 0, 0);
    }
    __syncthreads();
    if (more) {
      commit();
      __syncthreads();
    }
  }

  #pragma unroll
  for (int mi = 0; mi < 2; ++mi)
    #pragma unroll
    for (int n = 0; n < 4; ++n)
      #pragma unroll
      for (int j = 0; j < 4; ++j) {
        int rr = row0 + w * 32 + mi * 16 + g * 4 + j;
        int oo = col0 + n * 16 + c;
        Y[(size_t)rr * DMODEL + oo] = acc[mi][n][j] + bias[oo];
      }
}

// ---------------------------------------------------------------------------
// Flash attention on 32x32x16 fp16 MFMA, swapped operands, exp2 domain.
// Staging via global_load_lds: linear LDS dest, inverse-swizzled global source.
// ---------------------------------------------------------------------------
__global__ __launch_bounds__(256) void attn32(
    const unsigned short* __restrict__ qf, const unsigned short* __restrict__ kf,
    const unsigned short* __restrict__ vt, const unsigned long long* __restrict__ mbits,
    unsigned short* __restrict__ Ob)
{
  __shared__ __align__(16) unsigned short LDS[2][2][4096];   // 32 KB

  const int t = threadIdx.x;
  const int lane = t & 63;
  const int w = t >> 6;
  const int pair = w >> 1;
  const int chunk = w & 1;
  const int c31 = lane & 31;
  const int hi = lane >> 5;

  const int nwg = gridDim.x;
  const int bid = blockIdx.x;
  const int lin = (bid & 7) * (nwg >> 3) + (bid >> 3);
  const int qi = lin & 63;
  const int bh = lin >> 6;
  const int q0 = qi * 64;
  const int b = bh >> 3, h = bh & 7;
  const int qrow = q0 + pair * 32 + c31;

  const unsigned short* Qp = qf + ((size_t)bh * S_LEN + qrow) * HDIM;
  f16x8 qfr[4];
  #pragma unroll
  for (int s = 0; s < 4; ++s)
    qfr[s] = __builtin_bit_cast(f16x8, *(const u16x8*)(Qp + 16 * s + 8 * hi));

  const unsigned short* Kb = kf + (size_t)bh * S_LEN * HDIM;
  const unsigned short* Vbt = vt + (size_t)bh * HDIM * S_LEN;
  const unsigned long long* mptr = mbits + (size_t)(b * S_LEN + qrow) * NWORDS;

  // staging slots: wave w covers linear chunk idx = (w*2+i)*64 + lane, i=0,1.
  // linear LDS pos idx holds source chunk (lane&7)^row (swizzle involution).
  const int idx0 = (w * 2 + 0) * 64 + lane;
  const int idx1 = (w * 2 + 1) * 64 + lane;
  const int r0 = idx0 >> 3, r1 = idx1 >> 3;
  const int c0 = ((lane & 7) ^ r0) & 7, c1 = ((lane & 7) ^ r1) & 7;
  const unsigned short* nK0 = Kb + r0 * HDIM + c0 * 8;
  const unsigned short* nK1 = Kb + r1 * HDIM + c1 * 8;
  const unsigned short* nV0 = Vbt + (size_t)r0 * S_LEN + c0 * 8;
  const unsigned short* nV1 = Vbt + (size_t)r1 * S_LEN + c1 * 8;
  const int ld0 = (w * 2 + 0) * 512;   // short offset of this wave's 1KB region
  const int ld1 = (w * 2 + 1) * 512;

  auto issue = [&](int buf) {
    gload16(nK0, &LDS[buf][0][ld0]);
    gload16(nK1, &LDS[buf][0][ld1]);
    gload16(nV0, &LDS[buf][1][ld0]);
    gload16(nV1, &LDS[buf][1][ld1]);
    nK0 += 64 * HDIM; nK1 += 64 * HDIM;   // next KV tile: +64 rows
    nV0 += 64; nV1 += 64;                 // next KV tile: +64 cols
  };

  f32x16 oacc0, oacc1;
  #pragma unroll
  for (int r = 0; r < 16; ++r) { oacc0[r] = 0.f; oacc1[r] = 0.f; }
  const f32x16 fzero = oacc0;
  float mrow = -INFINITY, lrow = 0.f;

  unsigned long long m64 = mptr[0], m64n = 0;

  issue(0);
  __syncthreads();   // barrier drains vmcnt -> LDS[0] ready

  int cur = 0;
  for (int kt = 0; kt < S_LEN / 64; ++kt) {
    const bool more = kt < (S_LEN / 64 - 1);
    if (more) {
      issue(cur ^ 1);
      m64n = mptr[kt + 1];
    }
    const unsigned short* K_ = &LDS[cur][0][0];
    const unsigned short* Vt_ = &LDS[cur][1][0];

    // ---- scores (single fp16 pass) ----
    f32x16 p;
    __builtin_amdgcn_s_setprio(1);
    {
      int idx = swzi(chunk * 32 + c31, 8 * hi);
      f16x8 kfr = __builtin_bit_cast(f16x8, *(const u16x8*)&K_[idx]);
      p = __builtin_amdgcn_mfma_f32_32x32x16_f16(kfr, qfr[0], fzero, 0, 0, 0);
    }
    #pragma unroll
    for (int s = 1; s < 4; ++s) {
      int idx = swzi(chunk * 32 + c31, 16 * s + 8 * hi);
      f16x8 kfr = __builtin_bit_cast(f16x8, *(const u16x8*)&K_[idx]);
      p = __builtin_amdgcn_mfma_f32_32x32x16_f16(kfr, qfr[s], p, 0, 0, 0);
    }
    __builtin_amdgcn_s_setprio(0);

    // ---- mask BEFORE max (bfi blend to -1e9) ----
    unsigned half = chunk ? (unsigned)(m64 >> 32) : (unsigned)m64;
    unsigned hs = half >> (hi * 4);
    #pragma unroll
    for (int r = 0; r < 16; ++r) {
      int bs = (r & 3) + 8 * (r >> 2);
      p[r] = mask_blend(p[r], bit_mask(hs, bs));
    }

    // ---- masked row max ----
    float t0 = max3f(p[0], p[1], p[2]);
    float t1 = max3f(p[3], p[4], p[5]);
    float t2 = max3f(p[6], p[7], p[8]);
    float t3 = max3f(p[9], p[10], p[11]);
    float t4 = max3f(p[12], p[13], p[14]);
    float mx = fmaxf(max3f(t0, t1, t2), max3f(t3, t4, p[15]));
    mx = xhalf_max(mx);

    float mn, scl;
    if (__all(mx <= mrow + 11.54f)) {    // defer-max
      mn = mrow;
      scl = 1.0f;
    } else {
      mn = fmaxf(mrow, mx);
      scl = fast_exp2(mrow - mn);
      mrow = mn;
      oacc0 *= scl;
      oacc1 *= scl;
    }

    // ---- exp2 ----
    #pragma unroll
    for (int r = 0; r < 16; ++r) p[r] = fast_exp2(p[r] - mn);

    float s0_ = (p[0] + p[1]) + (p[2] + p[3]);
    float s1_ = (p[4] + p[5]) + (p[6] + p[7]);
    float s2_ = (p[8] + p[9]) + (p[10] + p[11]);
    float s3_ = (p[12] + p[13]) + (p[14] + p[15]);
    float ps = xhalf_sum((s0_ + s1_) + (s2_ + s3_));
    lrow = lrow * scl + ps;

    // ---- P redistribution (verified shfl_xor keep/send/recv) ----
    unsigned W[4][2];
    #pragma unroll
    for (int rq = 0; rq < 4; ++rq) {
      W[rq][0] = __builtin_bit_cast(unsigned, __builtin_amdgcn_cvt_pkrtz(p[4 * rq + 0], p[4 * rq + 1]));
      W[rq][1] = __builtin_bit_cast(unsigned, __builtin_amdgcn_cvt_pkrtz(p[4 * rq + 2], p[4 * rq + 3]));
    }
    f16x8 pf[2];
    #pragma unroll
    for (int s2 = 0; s2 < 2; ++s2) {
      unsigned keep0 = hi ? W[2 * s2 + 1][0] : W[2 * s2][0];
      unsigned keep1 = hi ? W[2 * s2 + 1][1] : W[2 * s2][1];
      unsigned send0 = hi ? W[2 * s2][0] : W[2 * s2 + 1][0];
      unsigned send1 = hi ? W[2 * s2][1] : W[2 * s2 + 1][1];
      unsigned recv0 = (unsigned)__shfl_xor((int)send0, 32, 64);
      unsigned recv1 = (unsigned)__shfl_xor((int)send1, 32, 64);
      u32x4 fw;
      fw[0] = hi ? recv0 : keep0;
      fw[1] = hi ? recv1 : keep1;
      fw[2] = hi ? keep0 : recv0;
      fw[3] = hi ? keep1 : recv1;
      pf[s2] = __builtin_bit_cast(f16x8, fw);
    }

    // ---- PV ----
    __builtin_amdgcn_s_setprio(1);
    #pragma unroll
    for (int s2 = 0; s2 < 2; ++s2) {
      int col = chunk * 32 + 16 * s2 + 8 * hi;
      f16x8 vf0 = __builtin_bit_cast(f16x8, *(const u16x8*)&Vt_[swzi(c31, col)]);
      f16x8 vf1 = __builtin_bit_cast(f16x8, *(const u16x8*)&Vt_[swzi(32 + c31, col)]);
      oacc0 = __builtin_amdgcn_mfma_f32_32x32x16_f16(vf0, pf[s2], oacc0, 0, 0, 0);
      oacc1 = __builtin_amdgcn_mfma_f32_32x32x16_f16(vf1, pf[s2], oacc1, 0, 0, 0);
    }
    __builtin_amdgcn_s_setprio(0);

    if (more) m64 = m64n;
    __syncthreads();   // drains gload_lds (vmcnt) + protects LDS[cur] reuse
    cur ^= 1;
  }

  // ---- flash merge across the wave pair, via LDS ----
  float* mb = (float*)&LDS[0][0][0];   // [2 pair][2 hi][32 c31][36]
  const int mi = ((pair * 2 + hi) * 32 + c31) * 36;
  if (chunk == 1) {
    #pragma unroll
    for (int q4 = 0; q4 < 4; ++q4) {
      *(f32x4*)&mb[mi + q4 * 4]      = (f32x4){oacc0[q4 * 4], oacc0[q4 * 4 + 1], oacc0[q4 * 4 + 2], oacc0[q4 * 4 + 3]};
      *(f32x4*)&mb[mi + 16 + q4 * 4] = (f32x4){oacc1[q4 * 4], oacc1[q4 * 4 + 1], oacc1[q4 * 4 + 2], oacc1[q4 * 4 + 3]};
    }
    mb[mi + 32] = mrow;
    mb[mi + 33] = lrow;
  }
  __syncthreads();
  if (chunk == 0) {
    float m1 = mb[mi + 32], l1 = mb[mi + 33];
    float mS = fmaxf(mrow, m1);
    float f0 = fast_exp2(mrow - mS), f1 = fast_exp2(m1 - mS);
    float lS = lrow * f0 + l1 * f1;
    float inv = 1.0f / lS;
    size_t obase = ((size_t)b * S_LEN + qrow) * DMODEL + h * HDIM;
    #pragma unroll
    for (int c2 = 0; c2 < 2; ++c2) {
      #pragma unroll
      for (int rq = 0; rq < 4; ++rq) {
        u16x4 hv;
        #pragma unroll
        for (int rb = 0; rb < 4; ++rb) {
          int reg = 4 * rq + rb;
          float o0 = (c2 == 0) ? oacc0[reg] : oacc1[reg];
          float o1 = mb[mi + c2 * 16 + reg];
          hv[rb] = f2bf((o0 * f0 + o1 * f1) * inv);
        }
        *(u16x4*)(Ob + obase + 32 * c2 + 8 * rq + 4 * hi) = hv;
      }
    }
  }
}

// ---------------------------------------------------------------------------
extern "C" void kernel_launch(void* const* d_in, const int* in_sizes, int n_in,
                              void* d_out, int out_size, void* d_ws, size_t ws_size,
                              hipStream_t stream) {
  const float* query = (const float*)d_in[0];
  const float* key   = (const float*)d_in[1];
  const float* value = (const float*)d_in[2];
  const int*   mask  = (const int*)  d_in[3];
  const float* Wq = (const float*)d_in[4];
  const float* bq = (const float*)d_in[5];
  const float* Wk = (const float*)d_in[6];
  const float* bk = (const float*)d_in[7];
  const float* Wv = (const float*)d_in[8];
  const float* bv = (const float*)d_in[9];
  const float* Wo = (const float*)d_in[10];
  const float* bo = (const float*)d_in[11];
  float* out = (float*)d_out;

  const size_t PER = (size_t)2 * S_LEN * DMODEL;   // 4,194,304 elements
  const size_t WSZ = (size_t)DMODEL * DMODEL;      // 262,144

  unsigned short* p = (unsigned short*)d_ws;
  unsigned short* wbuf = p;                        // [4][2][WSZ] = 4 MB
  unsigned short* xh = p + 8 * WSZ;                // q input hi / attn out
  unsigned short* xl = xh + PER;
  unsigned short* yh = xl + PER;                   // k input hi/lo
  unsigned short* yl = yh + PER;
  unsigned short* zh = yl + PER;                   // v input hi/lo
  unsigned short* zl = zh + PER;
  unsigned short* qfb = zl + PER;                  // fp16 Q (log2e-scaled)
  unsigned short* kfb = qfb + PER;                 // fp16 K
  unsigned short* vtb = kfb + PER;                 // fp16 V^T  (total 76 MB)

  unsigned short* woh = wbuf + 3 * 2 * WSZ;

  unsigned long long* bits = (unsigned long long*)d_out;   // overwritten by gemm_out

  prep<<<dim3(2048, 5), 256, 0, stream>>>(query, key, value, Wq, Wk, Wv, Wo, mask,
                                          xh, xl, yh, yl, zh, zl, wbuf, bits);

  proj_qkv<<<dim3(2 * S_LEN / 128, DMODEL / 64, 3), 256, 0, stream>>>(
      xh, xl, yh, yl, zh, zl, wbuf, bq, bk, bv, qfb, kfb, vtb);

  attn32<<<1024, 256, 0, stream>>>(qfb, kfb, vtb, bits, xh);

  gemm_out<<<dim3(2 * S_LEN / 128, DMODEL / 64), 256, 0, stream>>>(xh, woh, bo, out);
}